// Round 6
// baseline (1179.342 us; speedup 1.0000x reference)
//
#include <hip/hip_runtime.h>

#define NN 25000
#define HH 64
#define EE 400000
#define NH (NN*HH)
#define NNODES 25000

typedef __attribute__((ext_vector_type(8))) short bf16x8;
typedef __attribute__((ext_vector_type(4))) float f32x4;

__device__ __forceinline__ float silu_f(float x){
  return __fdividef(x, 1.0f + __expf(-x));
}
__device__ __forceinline__ short f2bf(float x){
  unsigned u = __float_as_uint(x);
  unsigned r = (u + 0x7FFFu + ((u>>16)&1u)) >> 16;
  return (short)r;
}
__device__ __forceinline__ float bf2f(short h){
  return __uint_as_float(((unsigned)(unsigned short)h)<<16);
}
// 4-term split product: (ah+al)(bh+bl) — error ~2^-18 relative
__device__ __forceinline__ f32x4 mfma4(bf16x8 ah, bf16x8 al, bf16x8 bh, bf16x8 bl, f32x4 acc){
  acc = __builtin_amdgcn_mfma_f32_16x16x32_bf16(ah, bh, acc, 0, 0, 0);
  acc = __builtin_amdgcn_mfma_f32_16x16x32_bf16(ah, bl, acc, 0, 0, 0);
  acc = __builtin_amdgcn_mfma_f32_16x16x32_bf16(al, bh, acc, 0, 0, 0);
  acc = __builtin_amdgcn_mfma_f32_16x16x32_bf16(al, bl, acc, 0, 0, 0);
  return acc;
}

__device__ __forceinline__ void mm3(float* __restrict__ C, const float* __restrict__ A,
                                    const float* __restrict__ B){
  #pragma unroll
  for (int i=0;i<3;i++)
    #pragma unroll
    for (int j=0;j<3;j++)
      C[i*3+j] = A[i*3+0]*B[0*3+j] + A[i*3+1]*B[1*3+j] + A[i*3+2]*B[2*3+j];
}
__device__ __forceinline__ void build3(float* __restrict__ M, const float* __restrict__ c){
  M[0] =  c[0]+c[4]; M[1] =  c[1]+c[5]; M[2] =  c[2]+c[6];
  M[3] = -c[1]+c[5]; M[4] =  c[0]+c[7]; M[5] =  c[3]+c[8];
  M[6] = -c[2]+c[6]; M[7] = -c[3]+c[8]; M[8] =  c[0]+c[9];
}
__device__ __forceinline__ void decomp3(const float* __restrict__ M, float* __restrict__ c){
  float I = (M[0]+M[4]+M[8]) * (1.0f/3.0f);
  c[0]=I;
  c[1]=0.5f*(M[1]-M[3]); c[2]=0.5f*(M[2]-M[6]); c[3]=0.5f*(M[5]-M[7]);
  c[4]=M[0]-I; c[5]=0.5f*(M[1]+M[3]); c[6]=0.5f*(M[2]+M[6]);
  c[7]=M[4]-I; c[8]=0.5f*(M[5]+M[7]); c[9]=M[8]-I;
}

// k_prep: normalize + decompose; writes plane-major XD (for GEMMs/final)
// and node-major XDi[node][c=0..8][64] (dense 2304B/node gather layout)
__global__ __launch_bounds__(256) void k_prep(const float* __restrict__ X, float* __restrict__ XD,
                                              float* __restrict__ XDi){
  int idx = blockIdx.x*256 + threadIdx.x;
  if (idx >= NH) return;
  const float* t = X + (size_t)idx*9;
  float m[9];
  float n2 = 0.f;
  #pragma unroll
  for (int i=0;i<9;i++){ m[i] = t[i]; n2 += m[i]*m[i]; }
  float inv = __fdividef(1.0f, n2 + 1.0f);
  #pragma unroll
  for (int i=0;i<9;i++) m[i] *= inv;
  float c[10]; decomp3(m, c);
  #pragma unroll
  for (int i=0;i<10;i++) XD[i*NH + idx] = c[i];
  int node = idx >> 6, lane = idx & 63;
  float* xb = XDi + (size_t)node*576 + lane;   // 576 = 9*64
  #pragma unroll
  for (int i=0;i<9;i++) xb[i*64] = c[i];
}

// pre-split MLP weights into bf16 hi/lo (runs every launch; deterministic)
__global__ __launch_bounds__(256) void k_prep_w(
    const float* __restrict__ W1, const float* __restrict__ W2, const float* __restrict__ W3,
    short* __restrict__ W1h, short* __restrict__ W1l,
    short* __restrict__ W2h, short* __restrict__ W2l,
    short* __restrict__ W3h, short* __restrict__ W3l){
  int i = blockIdx.x*256 + threadIdx.x;
  if (i < 2048){
    float v = W1[i]; short h = f2bf(v); W1h[i]=h; W1l[i]=f2bf(v - bf2f(h));
  } else if (i < 10240){
    int j = i - 2048;
    float v = W2[j]; short h = f2bf(v); W2h[j]=h; W2l[j]=f2bf(v - bf2f(h));
  } else if (i < 34816){
    int j = i - 10240;
    float v = W3[j]; short h = f2bf(v); W3h[j]=h; W3l[j]=f2bf(v - bf2f(h));
  }
}

// ---------------- counting sort of edges by destination node -------------
__global__ __launch_bounds__(256) void k_hist(const int* __restrict__ ei, int* __restrict__ cnt){
  int e = blockIdx.x*256 + threadIdx.x;
  if (e < EE) atomicAdd(&cnt[ei[e]], 1);
}

// exclusive prefix sum over cnt[NNODES] -> off (single workgroup)
__global__ __launch_bounds__(256) void k_scan(const int* __restrict__ cnt, int* __restrict__ off){
  __shared__ int part[256];
  const int tid = threadIdx.x;
  const int base = tid*98;                 // 256*98 = 25088 >= 25000
  int s = 0;
  for (int i=0;i<98;i++){ int idx=base+i; if (idx<NNODES) s += cnt[idx]; }
  part[tid]=s; __syncthreads();
  for (int d=1; d<256; d<<=1){
    int v = (tid>=d)? part[tid-d] : 0;
    __syncthreads();
    part[tid] += v;
    __syncthreads();
  }
  int run = (tid==0)? 0 : part[tid-1];
  for (int i=0;i<98;i++){
    int idx=base+i;
    if (idx<NNODES){ off[idx]=run; run += cnt[idx]; }
  }
}

// scatter edge ids into dst-sorted order.
// After this kernel, off[n] = END offset of node n's range (start = off[n]-cnt[n]).
__global__ __launch_bounds__(256) void k_scatter_perm(const int* __restrict__ ei,
                                                      int* __restrict__ off,
                                                      int* __restrict__ perm){
  int e = blockIdx.x*256 + threadIdx.x;
  if (e < EE){
    int p = atomicAdd(&off[ei[e]], 1);
    perm[p] = e;
  }
}

// ---------------- kernel A: edge MLP(32->64->128->192) -> F planes ----------
// block = 256 thr = 4 waves; 64 dst-sorted edges (slots [elo + b*64, ...)), 16/wave;
// barrier-free wave-private LDS slabs — identical MLP structure to the R2-passing
// fused kernel; P4 replaced by a coalesced F-plane store epilogue.
// F[c][p-elo][l], c in {0,1,2}; cap = chunk plane stride (CS*64 floats).
#define O_H1H 0
#define O_H1L 2304
#define O_H2H 4608
#define O_H2L 8960
#define O_EAH 4608
#define O_EAL 5888
#define O_F   0
#define O_CUT 13312
#define SLAB  13440
#define SMEM_BYTES (4*SLAB)

__global__ __launch_bounds__(256, 3) void k_edge_mlp(
    const float* __restrict__ ea, const float* __restrict__ ew,
    const int* __restrict__ perm,
    const short* __restrict__ W1h, const short* __restrict__ W1l, const float* __restrict__ b1,
    const short* __restrict__ W2h, const short* __restrict__ W2l, const float* __restrict__ b2,
    const short* __restrict__ W3h, const short* __restrict__ W3l, const float* __restrict__ b3,
    float* __restrict__ F, int elo, size_t cap)
{
  __shared__ char smem[SMEM_BYTES] __attribute__((aligned(16)));
  const int tid  = threadIdx.x;
  const int w    = tid >> 6;
  const int l    = tid & 63;
  const int quad = l >> 4;
  const int nin  = l & 15;
  const int el0  = blockIdx.x * 64 + w * 16;   // chunk-local slot of this wave
  const int e0   = elo + el0;                  // global sorted slot
  char* sb = smem + w * SLAB;

  // ---- P0: stage this wave's 16 edge_attr rows (hi/lo split) + cutoffs ----
  #pragma unroll
  for (int g=0; g<2; g++){                       // 128 float4 over EA [16][32]
    int gi = l + g*64;
    int row = gi >> 3, c4 = gi & 7;
    int er = perm[e0 + row];
    float4 v = *(const float4*)&ea[(size_t)er*32 + c4*4];
    int be = row*40 + c4*4;
    short h;
    h = f2bf(v.x); ((short*)(sb+O_EAH))[be+0]=h; ((short*)(sb+O_EAL))[be+0]=f2bf(v.x-bf2f(h));
    h = f2bf(v.y); ((short*)(sb+O_EAH))[be+1]=h; ((short*)(sb+O_EAL))[be+1]=f2bf(v.y-bf2f(h));
    h = f2bf(v.z); ((short*)(sb+O_EAH))[be+2]=h; ((short*)(sb+O_EAL))[be+2]=f2bf(v.z-bf2f(h));
    h = f2bf(v.w); ((short*)(sb+O_EAH))[be+3]=h; ((short*)(sb+O_EAL))[be+3]=f2bf(v.w-bf2f(h));
  }
  if (l < 16){
    float wv = ew[perm[e0 + l]];
    float c = 0.5f*(__cosf(wv*0.6283185307179586f)+1.0f);
    ((float*)(sb+O_CUT))[l] = (wv < 5.0f) ? c : 0.0f;
  }

  // ---- P1: H1 = silu(EA @ W1^T + b1), M=16 N=64 K=32 (wave-local) ----
  {
    bf16x8 ah = *(const bf16x8*)(sb + O_EAH + nin*80 + quad*16);
    bf16x8 al = *(const bf16x8*)(sb + O_EAL + nin*80 + quad*16);
    f32x4 acc[4];
    #pragma unroll
    for (int nt=0; nt<4; nt++){
      f32x4 z = {0.f,0.f,0.f,0.f};
      bf16x8 bh = *(const bf16x8*)&W1h[(nt*16+nin)*32 + quad*8];
      bf16x8 bl = *(const bf16x8*)&W1l[(nt*16+nin)*32 + quad*8];
      acc[nt] = mfma4(ah, al, bh, bl, z);
    }
    #pragma unroll
    for (int nt=0; nt<4; nt++){
      float bb = b1[nt*16+nin];
      #pragma unroll
      for (int r=0; r<4; r++){
        float v = silu_f(acc[nt][r] + bb);
        int row = quad*4 + r, col = nt*16 + nin;
        short hi = f2bf(v); short lo = f2bf(v - bf2f(hi));
        ((short*)(sb+O_H1H))[row*72 + col] = hi;
        ((short*)(sb+O_H1L))[row*72 + col] = lo;
      }
    }
  }

  // ---- P2: H2 = silu(H1 @ W2^T + b2), M=16 N=128 K=64 ----
  {
    f32x4 acc[8];
    #pragma unroll
    for (int i=0;i<8;i++){ f32x4 z = {0.f,0.f,0.f,0.f}; acc[i]=z; }
    #pragma unroll
    for (int kt=0; kt<2; kt++){
      bf16x8 ah = *(const bf16x8*)(sb + O_H1H + nin*144 + kt*64 + quad*16);
      bf16x8 al = *(const bf16x8*)(sb + O_H1L + nin*144 + kt*64 + quad*16);
      #pragma unroll
      for (int nt=0; nt<8; nt++){
        bf16x8 bh = *(const bf16x8*)&W2h[(nt*16+nin)*64 + kt*32 + quad*8];
        bf16x8 bl = *(const bf16x8*)&W2l[(nt*16+nin)*64 + kt*32 + quad*8];
        acc[nt] = mfma4(ah, al, bh, bl, acc[nt]);
      }
    }
    // H2 region aliases EA; EA dead after P1 frag loads (same wave, in-order LDS)
    #pragma unroll
    for (int nt=0; nt<8; nt++){
      float bb = b2[nt*16+nin];
      #pragma unroll
      for (int r=0; r<4; r++){
        float v = silu_f(acc[nt][r] + bb);
        int row = quad*4 + r, col = nt*16 + nin;
        short hi = f2bf(v); short lo = f2bf(v - bf2f(hi));
        ((short*)(sb+O_H2H))[row*136 + col] = hi;
        ((short*)(sb+O_H2L))[row*136 + col] = lo;
      }
    }
  }

  // ---- P3: F = silu(H2 @ W3^T + b3) * cutoff, M=16 N=192 K=128 ----
  f32x4 acc3[12];
  #pragma unroll
  for (int i=0;i<12;i++){ f32x4 z = {0.f,0.f,0.f,0.f}; acc3[i]=z; }
  #pragma unroll
  for (int kt=0; kt<4; kt++){
    bf16x8 ah = *(const bf16x8*)(sb + O_H2H + nin*272 + kt*64 + quad*16);
    bf16x8 al = *(const bf16x8*)(sb + O_H2L + nin*272 + kt*64 + quad*16);
    #pragma unroll
    for (int nt=0; nt<12; nt++){
      bf16x8 bh = *(const bf16x8*)&W3h[(nt*16+nin)*128 + kt*32 + quad*8];
      bf16x8 bl = *(const bf16x8*)&W3l[(nt*16+nin)*128 + kt*32 + quad*8];
      acc3[nt] = mfma4(ah, al, bh, bl, acc3[nt]);
    }
  }
  // F aliases H1+H2; all H2 reads above are same-wave and in-order
  #pragma unroll
  for (int nt=0; nt<12; nt++){
    float bb = b3[nt*16+nin];
    #pragma unroll
    for (int r=0; r<4; r++){
      int row = quad*4 + r, col = nt*16 + nin;
      float v = silu_f(acc3[nt][r] + bb) * ((float*)(sb+O_CUT))[row];
      ((float*)(sb+O_F))[row*196 + col] = v;
    }
  }

  // ---- epilogue: write F planes (coalesced 256B stores; lane = channel) ----
  #pragma unroll
  for (int t=0; t<16; t++){
    const float* fb = (const float*)(sb + O_F + t*784 + l*12);
    size_t pl = (size_t)(el0 + t)*64 + l;
    F[pl]         = fb[0];
    F[cap + pl]   = fb[1];
    F[2*cap + pl] = fb[2];
  }
}

// ---------------- kernel B: node-parallel aggregation, zero atomics ----------
// one wave per destination node; walks the part of its dst-sorted edge range
// inside [elo,ehi), gathers XDi[src], accumulates in registers, stores/adds Y.
// No LDS -> high occupancy hides gather latency. src via perm->ei 2-hop
// (wave-uniform broadcast loads; keeps workspace layout byte-identical to R2).
__global__ __launch_bounds__(256) void k_agg(
    const float* __restrict__ F, const int* __restrict__ offEnd,
    const int* __restrict__ cnt, const int* __restrict__ perm,
    const int* __restrict__ ei,
    const float* __restrict__ XDi, float* __restrict__ Y,
    int elo, int ehi, size_t cap)
{
  const int w = threadIdx.x >> 6;
  const int l = threadIdx.x & 63;
  const int n = blockIdx.x*4 + w;
  const int end   = offEnd[n];
  const int start = end - cnt[n];
  const int is = start > elo ? start : elo;
  const int ie = end   < ehi ? end   : ehi;
  if (is >= ie) return;
  float a0=0.f,a1=0.f,a2=0.f,a3=0.f,a4=0.f,a5=0.f,a6=0.f,a7=0.f,a8=0.f;
  for (int p=is; p<ie; ++p){
    int e = perm[p];            // wave-uniform
    int s = ei[EE + e];         // wave-uniform
    size_t fp = (size_t)(p - elo)*64 + l;
    float f0 = F[fp], f1 = F[cap+fp], f2 = F[2*cap+fp];
    const float* xb = XDi + (size_t)s*576 + l;
    a0 += f0*xb[0];
    a1 += f1*xb[64];  a2 += f1*xb[128]; a3 += f1*xb[192];
    a4 += f2*xb[256]; a5 += f2*xb[320]; a6 += f2*xb[384];
    a7 += f2*xb[448]; a8 += f2*xb[512];
  }
  float* yb = Y + (size_t)n*64 + l;
  if (start >= elo){   // chunk containing this node's range start: store
    yb[0*(size_t)NH]=a0; yb[1*(size_t)NH]=a1; yb[2*(size_t)NH]=a2;
    yb[3*(size_t)NH]=a3; yb[4*(size_t)NH]=a4; yb[5*(size_t)NH]=a5;
    yb[6*(size_t)NH]=a6; yb[7*(size_t)NH]=a7; yb[8*(size_t)NH]=a8;
  } else {             // continuation chunk: accumulate (launches serialize)
    yb[0*(size_t)NH]+=a0; yb[1*(size_t)NH]+=a1; yb[2*(size_t)NH]+=a2;
    yb[3*(size_t)NH]+=a3; yb[4*(size_t)NH]+=a4; yb[5*(size_t)NH]+=a5;
    yb[6*(size_t)NH]+=a6; yb[7*(size_t)NH]+=a7; yb[8*(size_t)NH]+=a8;
  }
}

// ---------------- node-side fp32 GEMM (plane channel mixing) -------------
template<int K, int KS, int NT, int TO, int NOUT>
__global__ __launch_bounds__(256) void k_gemm(const float* __restrict__ In,
                       const float* __restrict__ W,
                       float* __restrict__ Out, int M){
  constexpr int KSP = KS + 4;
  constexpr int F4R = KS/4;
  __shared__ __align__(16) float sA[128*KSP];
  __shared__ __align__(16) float sW[NT*KSP];
  const int tid = threadIdx.x;
  const int te = tid >> 4;
  const int to = tid & 15;
  const int e0 = blockIdx.x * 128;
  const int ob = blockIdx.y * NT;
  float acc[8][TO];
  #pragma unroll
  for (int s=0;s<8;s++)
    #pragma unroll
    for (int r=0;r<TO;r++) acc[s][r]=0.f;

  for (int kb = 0; kb < K; kb += KS){
    if (kb) __syncthreads();
    #pragma unroll
    for (int g = 0; g < 128*F4R/256; g++){
      int gi = tid + g*256;
      int row = gi / F4R, c4 = gi % F4R;
      float4 v = make_float4(0.f,0.f,0.f,0.f);
      if (e0 + row < M) v = *(const float4*)&In[(size_t)(e0+row)*K + kb + c4*4];
      int c4p = c4 ^ ((row>>3)&3);
      *(float4*)&sA[row*KSP + c4p*4] = v;
    }
    #pragma unroll
    for (int g = 0; g < NT*F4R/256; g++){
      int gi = tid + g*256;
      int row = gi / F4R, c4 = gi % F4R;
      float4 v = *(const float4*)&W[(size_t)(ob+row)*K + kb + c4*4];
      int c4p = c4 ^ ((row>>3)&3);
      *(float4*)&sW[row*KSP + c4p*4] = v;
    }
    __syncthreads();
    #pragma unroll 4
    for (int k4 = 0; k4 < F4R; k4++){
      float4 aa[8], ww[TO];
      #pragma unroll
      for (int s=0;s<8;s++){
        int row = te*8+s;
        aa[s] = *(const float4*)&sA[row*KSP + (k4 ^ ((row>>3)&3))*4];
      }
      #pragma unroll
      for (int r=0;r<TO;r++){
        int row = to*TO+r;
        ww[r] = *(const float4*)&sW[row*KSP + (k4 ^ ((row>>3)&3))*4];
      }
      #pragma unroll
      for (int s=0;s<8;s++)
        #pragma unroll
        for (int r=0;r<TO;r++){
          acc[s][r] += aa[s].x*ww[r].x;
          acc[s][r] += aa[s].y*ww[r].y;
          acc[s][r] += aa[s].z*ww[r].z;
          acc[s][r] += aa[s].w*ww[r].w;
        }
    }
  }
  #pragma unroll
  for (int s=0;s<8;s++){
    int eg = e0 + te*8 + s;
    if (eg >= M) continue;
    #pragma unroll
    for (int r=0;r<TO;r++){
      int o = ob + to*TO + r;
      Out[(size_t)eg*NOUT + o] = acc[s][r];
    }
  }
}

__global__ __launch_bounds__(256) void k_combine(const float* __restrict__ XI, const float* __restrict__ Y,
                          float* __restrict__ XM){
  int idx = blockIdx.x*256 + threadIdx.x;
  if (idx >= NH) return;
  float xi[10], yc[10];
  #pragma unroll
  for (int c=0;c<10;c++) xi[c]=XI[c*NH+idx];
  #pragma unroll
  for (int c=0;c<9;c++)  yc[c]=Y[c*NH+idx];
  yc[9] = -(yc[4]+yc[7]);        // S traceless: S22 = -(S00+S11)
  float Xin[9], Ym[9], Am[9], Bm[9];
  build3(Xin, xi); build3(Ym, yc);
  mm3(Am, Ym, Xin);
  mm3(Bm, Xin, Ym);
  float Xn[9]; float n2 = 0.f;
  #pragma unroll
  for (int i=0;i<9;i++){ Xn[i] = Am[i]+Bm[i]; n2 += Xn[i]*Xn[i]; }
  float inv = __fdividef(1.0f, n2 + 1.0f);
  #pragma unroll
  for (int i=0;i<9;i++) Xn[i] *= inv;
  float c[10]; decomp3(Xn, c);
  #pragma unroll
  for (int i=0;i<10;i++) XM[i*NH+idx] = c[i];
}

__global__ __launch_bounds__(256) void k_final(const float* __restrict__ XD, const float* __restrict__ XO,
                        const float* __restrict__ q, float* __restrict__ out){
  int idx = blockIdx.x*256 + threadIdx.x;
  if (idx >= NH) return;
  float xd[10], xo[10];
  #pragma unroll
  for (int c=0;c<10;c++){ xd[c]=XD[c*NH+idx]; xo[c]=XO[c*NH+idx]; }
  float Xn[9], dX[9], D2[9];
  build3(Xn, xd); build3(dX, xo);
  mm3(D2, dX, dX);
  float cf = 1.0f + 0.1f*q[idx>>6];
  float* o = out + (size_t)idx*9;
  #pragma unroll
  for (int i=0;i<9;i++) o[i] = Xn[i] + (dX[i]+D2[i])*cf;
}

extern "C" void kernel_launch(void* const* d_in, const int* in_sizes, int n_in,
                              void* d_out, int out_size, void* d_ws, size_t ws_size,
                              hipStream_t stream) {
  const float* X   = (const float*)d_in[0];
  const int*   ei  = (const int*)  d_in[1];
  const float* ew  = (const float*)d_in[2];
  const float* ea  = (const float*)d_in[3];
  const float* q   = (const float*)d_in[4];
  const float* W1  = (const float*)d_in[5];
  const float* b1  = (const float*)d_in[6];
  const float* W2  = (const float*)d_in[7];
  const float* b2  = (const float*)d_in[8];
  const float* W3  = (const float*)d_in[9];
  const float* b3  = (const float*)d_in[10];
  const float* WIi = (const float*)d_in[11];
  const float* WAi = (const float*)d_in[12];
  const float* WSi = (const float*)d_in[13];
  const float* WIo = (const float*)d_in[14];
  const float* WAo = (const float*)d_in[15];
  const float* WSo = (const float*)d_in[16];
  float* out = (float*)d_out;

  // ---- workspace layout: byte-identical to the R2/R3 PASSING layout ----
  float* ws = (float*)d_ws;
  float* XD = ws;                        // 10*NH floats
  float* Y  = XD + (size_t)10*NH;        // 10*NH (9 planes from agg; reused as XO)
  float* XI = Y  + (size_t)10*NH;        // 10*NH (F chunks early; XM later)
  short* WS = (short*)(XI + (size_t)10*NH);  // pre-split weights: 69632 shorts
  short* W1h = WS,         *W1l = WS + 2048;
  short* W2h = WS + 4096,  *W2l = WS + 12288;
  short* W3h = WS + 20480, *W3l = WS + 45056;
  int* cnt  = (int*)(WS + 69632);        // 25000 ints
  int* off  = cnt + NNODES;              // 25000 ints
  int* perm = off + NNODES;              // 400000 ints
  float* XDi = (float*)(perm + EE);      // 9*NH floats, node-major gather layout

  // F chunks live inside XI (dead until the GEMM phase):
  // CS*64*3 = 15,998,976 floats <= 16,000,000 (XI size). 5 chunks.
  const int  CS  = 83328;                // multiple of 64
  const size_t cap = (size_t)CS * 64;    // F plane stride (floats)
  float* F = XI;

  hipMemsetAsync(Y, 0, (size_t)9*NH*sizeof(float), stream);   // zero-degree nodes
  hipMemsetAsync(cnt, 0, (size_t)NNODES*sizeof(int), stream);
  k_prep_w<<<136, 256, 0, stream>>>(W1, W2, W3, W1h, W1l, W2h, W2l, W3h, W3l);
  k_prep<<<NH/256, 256, 0, stream>>>(X, XD, XDi);

  // counting sort of edges by destination
  k_hist<<<(EE+255)/256, 256, 0, stream>>>(ei, cnt);
  k_scan<<<1, 256, 0, stream>>>(cnt, off);
  k_scatter_perm<<<(EE+255)/256, 256, 0, stream>>>(ei, off, perm);

  // A/B pipeline per chunk (single stream serializes A_c -> B_c -> A_{c+1}):
  //  A: edge MLP -> F planes (LDS/MFMA-heavy, low occupancy by design)
  //  B: node-parallel gather/aggregate, zero atomics, max occupancy
  for (int elo = 0; elo < EE; elo += CS){
    int ehi = elo + CS; if (ehi > EE) ehi = EE;
    k_edge_mlp<<<(ehi-elo)/64, 256, 0, stream>>>(ea, ew, perm, W1h, W1l, b1,
                                                 W2h, W2l, b2, W3h, W3l, b3,
                                                 F, elo, cap);
    k_agg<<<NNODES/4, 256, 0, stream>>>(F, off, cnt, perm, ei, XDi, Y, elo, ehi, cap);
  }

  // Xin = tensor_linear(Xn): three plane GEMMs (proven template)
  k_gemm<64,64,64,4,64><<<dim3((NN   +127)/128,1),256,0,stream>>>(XD,                 WIi, XI,                 NN  );
  k_gemm<64,64,64,4,64><<<dim3((3*NN +127)/128,1),256,0,stream>>>(XD + (size_t)NH,    WAi, XI + (size_t)NH,    3*NN);
  k_gemm<64,64,64,4,64><<<dim3((6*NN +127)/128,1),256,0,stream>>>(XD + (size_t)4*NH,  WSi, XI + (size_t)4*NH,  6*NN);

  k_combine<<<NH/256, 256, 0, stream>>>(XI, Y, XI);   // XI now holds XM planes

  float* XO = Y;  // Y consumed; reuse as output-mix buffer
  k_gemm<64,64,64,4,64><<<dim3((NN   +127)/128,1),256,0,stream>>>(XI,                 WIo, XO,                 NN  );
  k_gemm<64,64,64,4,64><<<dim3((3*NN +127)/128,1),256,0,stream>>>(XI + (size_t)NH,    WAo, XO + (size_t)NH,    3*NN);
  k_gemm<64,64,64,4,64><<<dim3((6*NN +127)/128,1),256,0,stream>>>(XI + (size_t)4*NH,  WSo, XO + (size_t)4*NH,  6*NN);

  k_final<<<NH/256, 256, 0, stream>>>(XD, XO, q, out);
}

// Round 7
// 921.588 us; speedup vs baseline: 1.2797x; 1.2797x over previous
//
#include <hip/hip_runtime.h>

#define NN 25000
#define HH 64
#define EE 400000
#define NH (NN*HH)
#define NNODES 25000

typedef __attribute__((ext_vector_type(8))) short bf16x8;
typedef __attribute__((ext_vector_type(4))) float f32x4;

__device__ __forceinline__ float silu_f(float x){
  return __fdividef(x, 1.0f + __expf(-x));
}
__device__ __forceinline__ short f2bf(float x){
  unsigned u = __float_as_uint(x);
  unsigned r = (u + 0x7FFFu + ((u>>16)&1u)) >> 16;
  return (short)r;
}
__device__ __forceinline__ float bf2f(short h){
  return __uint_as_float(((unsigned)(unsigned short)h)<<16);
}
// 4-term split product: (ah+al)(bh+bl) — error ~2^-18 relative
__device__ __forceinline__ f32x4 mfma4(bf16x8 ah, bf16x8 al, bf16x8 bh, bf16x8 bl, f32x4 acc){
  acc = __builtin_amdgcn_mfma_f32_16x16x32_bf16(ah, bh, acc, 0, 0, 0);
  acc = __builtin_amdgcn_mfma_f32_16x16x32_bf16(ah, bl, acc, 0, 0, 0);
  acc = __builtin_amdgcn_mfma_f32_16x16x32_bf16(al, bh, acc, 0, 0, 0);
  acc = __builtin_amdgcn_mfma_f32_16x16x32_bf16(al, bl, acc, 0, 0, 0);
  return acc;
}

__device__ __forceinline__ void mm3(float* __restrict__ C, const float* __restrict__ A,
                                    const float* __restrict__ B){
  #pragma unroll
  for (int i=0;i<3;i++)
    #pragma unroll
    for (int j=0;j<3;j++)
      C[i*3+j] = A[i*3+0]*B[0*3+j] + A[i*3+1]*B[1*3+j] + A[i*3+2]*B[2*3+j];
}
__device__ __forceinline__ void build3(float* __restrict__ M, const float* __restrict__ c){
  M[0] =  c[0]+c[4]; M[1] =  c[1]+c[5]; M[2] =  c[2]+c[6];
  M[3] = -c[1]+c[5]; M[4] =  c[0]+c[7]; M[5] =  c[3]+c[8];
  M[6] = -c[2]+c[6]; M[7] = -c[3]+c[8]; M[8] =  c[0]+c[9];
}
__device__ __forceinline__ void decomp3(const float* __restrict__ M, float* __restrict__ c){
  float I = (M[0]+M[4]+M[8]) * (1.0f/3.0f);
  c[0]=I;
  c[1]=0.5f*(M[1]-M[3]); c[2]=0.5f*(M[2]-M[6]); c[3]=0.5f*(M[5]-M[7]);
  c[4]=M[0]-I; c[5]=0.5f*(M[1]+M[3]); c[6]=0.5f*(M[2]+M[6]);
  c[7]=M[4]-I; c[8]=0.5f*(M[5]+M[7]); c[9]=M[8]-I;
}

// k_prep: normalize + decompose; writes plane-major XD (for GEMMs/final)
// and node-major XDi[node][c=0..8][64] (dense 2304B/node gather layout for P4)
__global__ __launch_bounds__(256) void k_prep(const float* __restrict__ X, float* __restrict__ XD,
                                              float* __restrict__ XDi){
  int idx = blockIdx.x*256 + threadIdx.x;
  if (idx >= NH) return;
  const float* t = X + (size_t)idx*9;
  float m[9];
  float n2 = 0.f;
  #pragma unroll
  for (int i=0;i<9;i++){ m[i] = t[i]; n2 += m[i]*m[i]; }
  float inv = __fdividef(1.0f, n2 + 1.0f);
  #pragma unroll
  for (int i=0;i<9;i++) m[i] *= inv;
  float c[10]; decomp3(m, c);
  #pragma unroll
  for (int i=0;i<10;i++) XD[i*NH + idx] = c[i];
  int node = idx >> 6, lane = idx & 63;
  float* xb = XDi + (size_t)node*576 + lane;   // 576 = 9*64
  #pragma unroll
  for (int i=0;i<9;i++) xb[i*64] = c[i];
}

// pre-split MLP weights into bf16 hi/lo (runs every launch; deterministic)
__global__ __launch_bounds__(256) void k_prep_w(
    const float* __restrict__ W1, const float* __restrict__ W2, const float* __restrict__ W3,
    short* __restrict__ W1h, short* __restrict__ W1l,
    short* __restrict__ W2h, short* __restrict__ W2l,
    short* __restrict__ W3h, short* __restrict__ W3l){
  int i = blockIdx.x*256 + threadIdx.x;
  if (i < 2048){
    float v = W1[i]; short h = f2bf(v); W1h[i]=h; W1l[i]=f2bf(v - bf2f(h));
  } else if (i < 10240){
    int j = i - 2048;
    float v = W2[j]; short h = f2bf(v); W2h[j]=h; W2l[j]=f2bf(v - bf2f(h));
  } else if (i < 34816){
    int j = i - 10240;
    float v = W3[j]; short h = f2bf(v); W3h[j]=h; W3l[j]=f2bf(v - bf2f(h));
  }
}

// ---------------- counting sort of edges by destination node -------------
__global__ __launch_bounds__(256) void k_hist(const int* __restrict__ ei, int* __restrict__ cnt){
  int e = blockIdx.x*256 + threadIdx.x;
  if (e < EE) atomicAdd(&cnt[ei[e]], 1);
}

// exclusive prefix sum over cnt[NNODES] -> off (single workgroup)
__global__ __launch_bounds__(256) void k_scan(const int* __restrict__ cnt, int* __restrict__ off){
  __shared__ int part[256];
  const int tid = threadIdx.x;
  const int base = tid*98;                 // 256*98 = 25088 >= 25000
  int s = 0;
  for (int i=0;i<98;i++){ int idx=base+i; if (idx<NNODES) s += cnt[idx]; }
  part[tid]=s; __syncthreads();
  for (int d=1; d<256; d<<=1){
    int v = (tid>=d)? part[tid-d] : 0;
    __syncthreads();
    part[tid] += v;
    __syncthreads();
  }
  int run = (tid==0)? 0 : part[tid-1];
  for (int i=0;i<98;i++){
    int idx=base+i;
    if (idx<NNODES){ off[idx]=run; run += cnt[idx]; }
  }
}

__global__ __launch_bounds__(256) void k_scatter_perm(const int* __restrict__ ei,
                                                      int* __restrict__ off,
                                                      int* __restrict__ perm){
  int e = blockIdx.x*256 + threadIdx.x;
  if (e < EE){
    int p = atomicAdd(&off[ei[e]], 1);
    perm[p] = e;
  }
}

// ---------------- fused edge pipeline: MLP(32->64->128->192) + segmented scatter ----------
// R7 restructure: block = 256 thr = 4 waves = 2 wave-PAIRS; each pair shares ONE
// 16-edge slab (13440 B) and splits the N-columns of every MLP layer (wave half=0
// takes the lower nt tiles, half=1 the upper). LDS/wave halves: 6720 B ->
// 6 blocks/CU = 24 waves/CU (launch_bounds(256,6)) vs 12 before — the MLP is
// latency-bound (R6 counters: MfmaUtil 8%, VALUBusy 19%, Occ 25%), so 2x resident
// waves is the lever. A-fragments span all K (both column halves) -> 5 block
// barriers between phases (symmetric work, amortized at high occupancy).
// Slab layout (bytes), identical to proven R2:
//  H1 hi/lo:  0 / 2304          (16 rows x 72 shorts)   ends 4608
//  H2 hi/lo:  4608 / 8960       (16 rows x 136 shorts)  ends 13312
//  EA hi/lo:  4608 / 5888       (alias H2; EA dead before H2 written)
//  F fp32:    0 (16 x 196)      aliases H1+H2, written after last H2 read
//  cut:       13312 (16 f32)
#define O_H1H 0
#define O_H1L 2304
#define O_H2H 4608
#define O_H2L 8960
#define O_EAH 4608
#define O_EAL 5888
#define O_F   0
#define O_CUT 13312
#define SLAB  13440
#define SMEM_BYTES (2*SLAB)

__global__ __launch_bounds__(256, 6) void k_edge_fused(
    const float* __restrict__ ea, const float* __restrict__ ew,
    const int* __restrict__ ei, const int* __restrict__ perm,
    const short* __restrict__ W1h, const short* __restrict__ W1l, const float* __restrict__ b1,
    const short* __restrict__ W2h, const short* __restrict__ W2l, const float* __restrict__ b2,
    const short* __restrict__ W3h, const short* __restrict__ W3l, const float* __restrict__ b3,
    const float* __restrict__ XDi, float* __restrict__ Y)
{
  __shared__ char smem[SMEM_BYTES] __attribute__((aligned(16)));
  const int tid  = threadIdx.x;
  const int w    = tid >> 6;
  const int l    = tid & 63;
  const int quad = l >> 4;
  const int nin  = l & 15;
  const int g    = w >> 1;          // slab / edge-group id (2 groups of 16 edges)
  const int half = w & 1;           // column-half of this wave within the pair
  const int e0   = blockIdx.x * 32 + g * 16;   // group's first sorted slot
  char* sb = smem + g * SLAB;

  // ---- prefetch this wave's 8 P4 edges (sorted slots e0 + half*8 + t) ----
  int eT[8], dT[8], sT[8];
  #pragma unroll
  for (int t=0;t<8;t++) eT[t] = perm[e0 + half*8 + t];
  #pragma unroll
  for (int t=0;t<8;t++){ dT[t] = ei[eT[t]]; sT[t] = ei[EE + eT[t]]; }

  // ---- P0: pair cooperatively stages the group's 16 EA rows (8 per wave) ----
  {
    int gi = l + half*64;                       // 128 float4 over EA [16][32]
    int row = gi >> 3, c4 = gi & 7;
    int er = perm[e0 + row];
    float4 v = *(const float4*)&ea[(size_t)er*32 + c4*4];
    int be = row*40 + c4*4;
    short h;
    h = f2bf(v.x); ((short*)(sb+O_EAH))[be+0]=h; ((short*)(sb+O_EAL))[be+0]=f2bf(v.x-bf2f(h));
    h = f2bf(v.y); ((short*)(sb+O_EAH))[be+1]=h; ((short*)(sb+O_EAL))[be+1]=f2bf(v.y-bf2f(h));
    h = f2bf(v.z); ((short*)(sb+O_EAH))[be+2]=h; ((short*)(sb+O_EAL))[be+2]=f2bf(v.z-bf2f(h));
    h = f2bf(v.w); ((short*)(sb+O_EAH))[be+3]=h; ((short*)(sb+O_EAL))[be+3]=f2bf(v.w-bf2f(h));
  }
  if (half == 0 && l < 16){
    float wv = ew[perm[e0 + l]];
    float c = 0.5f*(__cosf(wv*0.6283185307179586f)+1.0f);
    ((float*)(sb+O_CUT))[l] = (wv < 5.0f) ? c : 0.0f;
  }
  __syncthreads();

  // ---- P1: H1 = silu(EA @ W1^T + b1), M=16 N=64 K=32; this wave: 2 nt tiles ----
  {
    bf16x8 ah = *(const bf16x8*)(sb + O_EAH + nin*80 + quad*16);
    bf16x8 al = *(const bf16x8*)(sb + O_EAL + nin*80 + quad*16);
    f32x4 acc[2];
    #pragma unroll
    for (int i=0; i<2; i++){
      int nt = half*2 + i;
      f32x4 z = {0.f,0.f,0.f,0.f};
      bf16x8 bh = *(const bf16x8*)&W1h[(nt*16+nin)*32 + quad*8];
      bf16x8 bl = *(const bf16x8*)&W1l[(nt*16+nin)*32 + quad*8];
      acc[i] = mfma4(ah, al, bh, bl, z);
    }
    #pragma unroll
    for (int i=0; i<2; i++){
      int nt = half*2 + i;
      float bb = b1[nt*16+nin];
      #pragma unroll
      for (int r=0; r<4; r++){
        float v = silu_f(acc[i][r] + bb);
        int row = quad*4 + r, col = nt*16 + nin;
        short hi = f2bf(v); short lo = f2bf(v - bf2f(hi));
        ((short*)(sb+O_H1H))[row*72 + col] = hi;
        ((short*)(sb+O_H1L))[row*72 + col] = lo;
      }
    }
  }
  __syncthreads();

  // ---- P2: H2 = silu(H1 @ W2^T + b2), M=16 N=128 K=64; this wave: 4 nt tiles ----
  {
    f32x4 acc[4];
    #pragma unroll
    for (int i=0;i<4;i++){ f32x4 z = {0.f,0.f,0.f,0.f}; acc[i]=z; }
    #pragma unroll
    for (int kt=0; kt<2; kt++){
      bf16x8 ah = *(const bf16x8*)(sb + O_H1H + nin*144 + kt*64 + quad*16);
      bf16x8 al = *(const bf16x8*)(sb + O_H1L + nin*144 + kt*64 + quad*16);
      #pragma unroll
      for (int i=0; i<4; i++){
        int nt = half*4 + i;
        bf16x8 bh = *(const bf16x8*)&W2h[(nt*16+nin)*64 + kt*32 + quad*8];
        bf16x8 bl = *(const bf16x8*)&W2l[(nt*16+nin)*64 + kt*32 + quad*8];
        acc[i] = mfma4(ah, al, bh, bl, acc[i]);
      }
    }
    // H2 region aliases EA; EA reads all completed before the P1 barrier
    #pragma unroll
    for (int i=0; i<4; i++){
      int nt = half*4 + i;
      float bb = b2[nt*16+nin];
      #pragma unroll
      for (int r=0; r<4; r++){
        float v = silu_f(acc[i][r] + bb);
        int row = quad*4 + r, col = nt*16 + nin;
        short hi = f2bf(v); short lo = f2bf(v - bf2f(hi));
        ((short*)(sb+O_H2H))[row*136 + col] = hi;
        ((short*)(sb+O_H2L))[row*136 + col] = lo;
      }
    }
  }
  __syncthreads();

  // ---- P3: F = silu(H2 @ W3^T + b3) * cutoff, M=16 N=192 K=128; 6 nt/wave ----
  f32x4 acc3[6];
  #pragma unroll
  for (int i=0;i<6;i++){ f32x4 z = {0.f,0.f,0.f,0.f}; acc3[i]=z; }
  #pragma unroll
  for (int kt=0; kt<4; kt++){
    bf16x8 ah = *(const bf16x8*)(sb + O_H2H + nin*272 + kt*64 + quad*16);
    bf16x8 al = *(const bf16x8*)(sb + O_H2L + nin*272 + kt*64 + quad*16);
    #pragma unroll
    for (int i=0; i<6; i++){
      int nt = half*6 + i;
      bf16x8 bh = *(const bf16x8*)&W3h[(nt*16+nin)*128 + kt*32 + quad*8];
      bf16x8 bl = *(const bf16x8*)&W3l[(nt*16+nin)*128 + kt*32 + quad*8];
      acc3[i] = mfma4(ah, al, bh, bl, acc3[i]);
    }
  }
  __syncthreads();               // ALL waves' H1/H2 frag reads done; F may overwrite
  #pragma unroll
  for (int i=0; i<6; i++){
    int nt = half*6 + i;
    float bb = b3[nt*16+nin];
    #pragma unroll
    for (int r=0; r<4; r++){
      int row = quad*4 + r, col = nt*16 + nin;
      float v = silu_f(acc3[i][r] + bb) * ((float*)(sb+O_CUT))[row];
      ((float*)(sb+O_F))[row*196 + col] = v;
    }
  }
  __syncthreads();               // full F visible to P4

  // ---- P4: segmented scatter — this wave's 8 sorted edges; run-accumulate in
  //          registers, one atomic flush per run (runs split at the 8-edge
  //          boundary just add one extra flush — atomics sum correctly) ----
  {
    float acc[9];
    int cur = -1;
    #pragma unroll
    for (int t=0; t<8; t++){
      int el = half*8 + t;
      const float* fb = (const float*)(sb + O_F + el*784 + l*12);
      float f0 = fb[0], f1 = fb[1], f2 = fb[2];
      const float* xb = XDi + (size_t)sT[t]*576 + l;
      if (dT[t] != cur){                       // wave-uniform branch
        if (cur >= 0){
          int dst = cur*64 + l;
          #pragma unroll
          for (int c=0;c<9;c++) atomicAdd(&Y[c*NH+dst], acc[c]);
        }
        cur = dT[t];
        #pragma unroll
        for (int c=0;c<9;c++) acc[c] = 0.f;
      }
      acc[0] += f0*xb[0*64];
      acc[1] += f1*xb[1*64];
      acc[2] += f1*xb[2*64];
      acc[3] += f1*xb[3*64];
      acc[4] += f2*xb[4*64];
      acc[5] += f2*xb[5*64];
      acc[6] += f2*xb[6*64];
      acc[7] += f2*xb[7*64];
      acc[8] += f2*xb[8*64];
    }
    int dst = cur*64 + l;
    #pragma unroll
    for (int c=0;c<9;c++) atomicAdd(&Y[c*NH+dst], acc[c]);
  }
}

// ---------------- node-side fp32 GEMM (plane channel mixing) -------------
template<int K, int KS, int NT, int TO, int NOUT>
__global__ __launch_bounds__(256) void k_gemm(const float* __restrict__ In,
                       const float* __restrict__ W,
                       float* __restrict__ Out, int M){
  constexpr int KSP = KS + 4;
  constexpr int F4R = KS/4;
  __shared__ __align__(16) float sA[128*KSP];
  __shared__ __align__(16) float sW[NT*KSP];
  const int tid = threadIdx.x;
  const int te = tid >> 4;
  const int to = tid & 15;
  const int e0 = blockIdx.x * 128;
  const int ob = blockIdx.y * NT;
  float acc[8][TO];
  #pragma unroll
  for (int s=0;s<8;s++)
    #pragma unroll
    for (int r=0;r<TO;r++) acc[s][r]=0.f;

  for (int kb = 0; kb < K; kb += KS){
    if (kb) __syncthreads();
    #pragma unroll
    for (int g = 0; g < 128*F4R/256; g++){
      int gi = tid + g*256;
      int row = gi / F4R, c4 = gi % F4R;
      float4 v = make_float4(0.f,0.f,0.f,0.f);
      if (e0 + row < M) v = *(const float4*)&In[(size_t)(e0+row)*K + kb + c4*4];
      int c4p = c4 ^ ((row>>3)&3);
      *(float4*)&sA[row*KSP + c4p*4] = v;
    }
    #pragma unroll
    for (int g = 0; g < NT*F4R/256; g++){
      int gi = tid + g*256;
      int row = gi / F4R, c4 = gi % F4R;
      float4 v = *(const float4*)&W[(size_t)(ob+row)*K + kb + c4*4];
      int c4p = c4 ^ ((row>>3)&3);
      *(float4*)&sW[row*KSP + c4p*4] = v;
    }
    __syncthreads();
    #pragma unroll 4
    for (int k4 = 0; k4 < F4R; k4++){
      float4 aa[8], ww[TO];
      #pragma unroll
      for (int s=0;s<8;s++){
        int row = te*8+s;
        aa[s] = *(const float4*)&sA[row*KSP + (k4 ^ ((row>>3)&3))*4];
      }
      #pragma unroll
      for (int r=0;r<TO;r++){
        int row = to*TO+r;
        ww[r] = *(const float4*)&sW[row*KSP + (k4 ^ ((row>>3)&3))*4];
      }
      #pragma unroll
      for (int s=0;s<8;s++)
        #pragma unroll
        for (int r=0;r<TO;r++){
          acc[s][r] += aa[s].x*ww[r].x;
          acc[s][r] += aa[s].y*ww[r].y;
          acc[s][r] += aa[s].z*ww[r].z;
          acc[s][r] += aa[s].w*ww[r].w;
        }
    }
  }
  #pragma unroll
  for (int s=0;s<8;s++){
    int eg = e0 + te*8 + s;
    if (eg >= M) continue;
    #pragma unroll
    for (int r=0;r<TO;r++){
      int o = ob + to*TO + r;
      Out[(size_t)eg*NOUT + o] = acc[s][r];
    }
  }
}

__global__ __launch_bounds__(256) void k_combine(const float* __restrict__ XI, const float* __restrict__ Y,
                          float* __restrict__ XM){
  int idx = blockIdx.x*256 + threadIdx.x;
  if (idx >= NH) return;
  float xi[10], yc[10];
  #pragma unroll
  for (int c=0;c<10;c++) xi[c]=XI[c*NH+idx];
  #pragma unroll
  for (int c=0;c<9;c++)  yc[c]=Y[c*NH+idx];
  yc[9] = -(yc[4]+yc[7]);        // S traceless: S22 = -(S00+S11)
  float Xin[9], Ym[9], Am[9], Bm[9];
  build3(Xin, xi); build3(Ym, yc);
  mm3(Am, Ym, Xin);
  mm3(Bm, Xin, Ym);
  float Xn[9]; float n2 = 0.f;
  #pragma unroll
  for (int i=0;i<9;i++){ Xn[i] = Am[i]+Bm[i]; n2 += Xn[i]*Xn[i]; }
  float inv = __fdividef(1.0f, n2 + 1.0f);
  #pragma unroll
  for (int i=0;i<9;i++) Xn[i] *= inv;
  float c[10]; decomp3(Xn, c);
  #pragma unroll
  for (int i=0;i<10;i++) XM[i*NH+idx] = c[i];
}

__global__ __launch_bounds__(256) void k_final(const float* __restrict__ XD, const float* __restrict__ XO,
                        const float* __restrict__ q, float* __restrict__ out){
  int idx = blockIdx.x*256 + threadIdx.x;
  if (idx >= NH) return;
  float xd[10], xo[10];
  #pragma unroll
  for (int c=0;c<10;c++){ xd[c]=XD[c*NH+idx]; xo[c]=XO[c*NH+idx]; }
  float Xn[9], dX[9], D2[9];
  build3(Xn, xd); build3(dX, xo);
  mm3(D2, dX, dX);
  float cf = 1.0f + 0.1f*q[idx>>6];
  float* o = out + (size_t)idx*9;
  #pragma unroll
  for (int i=0;i<9;i++) o[i] = Xn[i] + (dX[i]+D2[i])*cf;
}

extern "C" void kernel_launch(void* const* d_in, const int* in_sizes, int n_in,
                              void* d_out, int out_size, void* d_ws, size_t ws_size,
                              hipStream_t stream) {
  const float* X   = (const float*)d_in[0];
  const int*   ei  = (const int*)  d_in[1];
  const float* ew  = (const float*)d_in[2];
  const float* ea  = (const float*)d_in[3];
  const float* q   = (const float*)d_in[4];
  const float* W1  = (const float*)d_in[5];
  const float* b1  = (const float*)d_in[6];
  const float* W2  = (const float*)d_in[7];
  const float* b2  = (const float*)d_in[8];
  const float* W3  = (const float*)d_in[9];
  const float* b3  = (const float*)d_in[10];
  const float* WIi = (const float*)d_in[11];
  const float* WAi = (const float*)d_in[12];
  const float* WSi = (const float*)d_in[13];
  const float* WIo = (const float*)d_in[14];
  const float* WAo = (const float*)d_in[15];
  const float* WSo = (const float*)d_in[16];
  float* out = (float*)d_out;

  // ---- workspace layout: byte-identical to the proven R2/R3 layout ----
  float* ws = (float*)d_ws;
  float* XD = ws;                        // 10*NH floats
  float* Y  = XD + (size_t)10*NH;        // 10*NH (9 planes used by agg; reused as XO)
  float* XI = Y  + (size_t)10*NH;        // 10*NH (later holds XM)
  short* WS = (short*)(XI + (size_t)10*NH);  // pre-split weights: 69632 shorts
  short* W1h = WS,         *W1l = WS + 2048;
  short* W2h = WS + 4096,  *W2l = WS + 12288;
  short* W3h = WS + 20480, *W3l = WS + 45056;
  int* cnt  = (int*)(WS + 69632);        // 25000 ints
  int* off  = cnt + NNODES;              // 25000 ints
  int* perm = off + NNODES;              // 400000 ints
  float* XDi = (float*)(perm + EE);      // 9*NH floats, node-major gather layout

  hipMemsetAsync(Y, 0, (size_t)9*NH*sizeof(float), stream);
  hipMemsetAsync(cnt, 0, (size_t)NNODES*sizeof(int), stream);
  k_prep_w<<<136, 256, 0, stream>>>(W1, W2, W3, W1h, W1l, W2h, W2l, W3h, W3l);
  k_prep<<<NH/256, 256, 0, stream>>>(X, XD, XDi);

  // counting sort of edges by destination (enables segmented scatter)
  k_hist<<<(EE+255)/256, 256, 0, stream>>>(ei, cnt);
  k_scan<<<1, 256, 0, stream>>>(cnt, off);
  k_scatter_perm<<<(EE+255)/256, 256, 0, stream>>>(ei, off, perm);

  // fused edge pipeline: MLP + cutoff + gather/segmented-scatter
  // (wave-pair column-split slabs, 24 waves/CU)
  k_edge_fused<<<EE/32, 256, 0, stream>>>(ea, ew, ei, perm, W1h, W1l, b1, W2h, W2l, b2,
                                          W3h, W3l, b3, XDi, Y);

  // Xin = tensor_linear(Xn): three plane GEMMs (I / A / S share their W)
  k_gemm<64,64,64,4,64><<<dim3((NN   +127)/128,1),256,0,stream>>>(XD,                 WIi, XI,                 NN  );
  k_gemm<64,64,64,4,64><<<dim3((3*NN +127)/128,1),256,0,stream>>>(XD + (size_t)NH,    WAi, XI + (size_t)NH,    3*NN);
  k_gemm<64,64,64,4,64><<<dim3((6*NN +127)/128,1),256,0,stream>>>(XD + (size_t)4*NH,  WSi, XI + (size_t)4*NH,  6*NN);

  k_combine<<<NH/256, 256, 0, stream>>>(XI, Y, XI);   // XI now holds XM planes

  float* XO = Y;  // Y consumed; reuse as output-mix buffer
  k_gemm<64,64,64,4,64><<<dim3((NN   +127)/128,1),256,0,stream>>>(XI,                 WIo, XO,                 NN  );
  k_gemm<64,64,64,4,64><<<dim3((3*NN +127)/128,1),256,0,stream>>>(XI + (size_t)NH,    WAo, XO + (size_t)NH,    3*NN);
  k_gemm<64,64,64,4,64><<<dim3((6*NN +127)/128,1),256,0,stream>>>(XI + (size_t)4*NH,  WSo, XO + (size_t)4*NH,  6*NN);

  k_final<<<NH/256, 256, 0, stream>>>(XD, XO, q, out);
}

// Round 8
// 658.495 us; speedup vs baseline: 1.7910x; 1.3995x over previous
//
#include <hip/hip_runtime.h>

#define NN 25000
#define HH 64
#define EE 400000
#define NH (NN*HH)
#define NNODES 25000

typedef __attribute__((ext_vector_type(8))) short bf16x8;
typedef __attribute__((ext_vector_type(4))) float f32x4;

__device__ __forceinline__ float silu_f(float x){
  return __fdividef(x, 1.0f + __expf(-x));
}
__device__ __forceinline__ short f2bf(float x){
  unsigned u = __float_as_uint(x);
  unsigned r = (u + 0x7FFFu + ((u>>16)&1u)) >> 16;
  return (short)r;
}
__device__ __forceinline__ float bf2f(short h){
  return __uint_as_float(((unsigned)(unsigned short)h)<<16);
}
// 4-term split product: (ah+al)(bh+bl) — error ~2^-18 relative
__device__ __forceinline__ f32x4 mfma4(bf16x8 ah, bf16x8 al, bf16x8 bh, bf16x8 bl, f32x4 acc){
  acc = __builtin_amdgcn_mfma_f32_16x16x32_bf16(ah, bh, acc, 0, 0, 0);
  acc = __builtin_amdgcn_mfma_f32_16x16x32_bf16(ah, bl, acc, 0, 0, 0);
  acc = __builtin_amdgcn_mfma_f32_16x16x32_bf16(al, bh, acc, 0, 0, 0);
  acc = __builtin_amdgcn_mfma_f32_16x16x32_bf16(al, bl, acc, 0, 0, 0);
  return acc;
}

__device__ __forceinline__ void mm3(float* __restrict__ C, const float* __restrict__ A,
                                    const float* __restrict__ B){
  #pragma unroll
  for (int i=0;i<3;i++)
    #pragma unroll
    for (int j=0;j<3;j++)
      C[i*3+j] = A[i*3+0]*B[0*3+j] + A[i*3+1]*B[1*3+j] + A[i*3+2]*B[2*3+j];
}
__device__ __forceinline__ void build3(float* __restrict__ M, const float* __restrict__ c){
  M[0] =  c[0]+c[4]; M[1] =  c[1]+c[5]; M[2] =  c[2]+c[6];
  M[3] = -c[1]+c[5]; M[4] =  c[0]+c[7]; M[5] =  c[3]+c[8];
  M[6] = -c[2]+c[6]; M[7] = -c[3]+c[8]; M[8] =  c[0]+c[9];
}
__device__ __forceinline__ void decomp3(const float* __restrict__ M, float* __restrict__ c){
  float I = (M[0]+M[4]+M[8]) * (1.0f/3.0f);
  c[0]=I;
  c[1]=0.5f*(M[1]-M[3]); c[2]=0.5f*(M[2]-M[6]); c[3]=0.5f*(M[5]-M[7]);
  c[4]=M[0]-I; c[5]=0.5f*(M[1]+M[3]); c[6]=0.5f*(M[2]+M[6]);
  c[7]=M[4]-I; c[8]=0.5f*(M[5]+M[7]); c[9]=M[8]-I;
}

// k_prep: normalize + decompose; writes plane-major XD (for GEMMs/final)
// and node-major XDi[node][c=0..8][64] (dense 2304B/node gather layout for P4)
__global__ __launch_bounds__(256) void k_prep(const float* __restrict__ X, float* __restrict__ XD,
                                              float* __restrict__ XDi){
  int idx = blockIdx.x*256 + threadIdx.x;
  if (idx >= NH) return;
  const float* t = X + (size_t)idx*9;
  float m[9];
  float n2 = 0.f;
  #pragma unroll
  for (int i=0;i<9;i++){ m[i] = t[i]; n2 += m[i]*m[i]; }
  float inv = __fdividef(1.0f, n2 + 1.0f);
  #pragma unroll
  for (int i=0;i<9;i++) m[i] *= inv;
  float c[10]; decomp3(m, c);
  #pragma unroll
  for (int i=0;i<10;i++) XD[i*NH + idx] = c[i];
  int node = idx >> 6, lane = idx & 63;
  float* xb = XDi + (size_t)node*576 + lane;   // 576 = 9*64
  #pragma unroll
  for (int i=0;i<9;i++) xb[i*64] = c[i];
}

// pre-split MLP weights into bf16 hi/lo (runs every launch; deterministic)
__global__ __launch_bounds__(256) void k_prep_w(
    const float* __restrict__ W1, const float* __restrict__ W2, const float* __restrict__ W3,
    short* __restrict__ W1h, short* __restrict__ W1l,
    short* __restrict__ W2h, short* __restrict__ W2l,
    short* __restrict__ W3h, short* __restrict__ W3l){
  int i = blockIdx.x*256 + threadIdx.x;
  if (i < 2048){
    float v = W1[i]; short h = f2bf(v); W1h[i]=h; W1l[i]=f2bf(v - bf2f(h));
  } else if (i < 10240){
    int j = i - 2048;
    float v = W2[j]; short h = f2bf(v); W2h[j]=h; W2l[j]=f2bf(v - bf2f(h));
  } else if (i < 34816){
    int j = i - 10240;
    float v = W3[j]; short h = f2bf(v); W3h[j]=h; W3l[j]=f2bf(v - bf2f(h));
  }
}

// ---------------- counting sort of edges by destination node -------------
__global__ __launch_bounds__(256) void k_hist(const int* __restrict__ ei, int* __restrict__ cnt){
  int e = blockIdx.x*256 + threadIdx.x;
  if (e < EE) atomicAdd(&cnt[ei[e]], 1);
}

// exclusive prefix sum over cnt[NNODES] -> off (single workgroup)
__global__ __launch_bounds__(256) void k_scan(const int* __restrict__ cnt, int* __restrict__ off){
  __shared__ int part[256];
  const int tid = threadIdx.x;
  const int base = tid*98;                 // 256*98 = 25088 >= 25000
  int s = 0;
  for (int i=0;i<98;i++){ int idx=base+i; if (idx<NNODES) s += cnt[idx]; }
  part[tid]=s; __syncthreads();
  for (int d=1; d<256; d<<=1){
    int v = (tid>=d)? part[tid-d] : 0;
    __syncthreads();
    part[tid] += v;
    __syncthreads();
  }
  int run = (tid==0)? 0 : part[tid-1];
  for (int i=0;i<98;i++){
    int idx=base+i;
    if (idx<NNODES){ off[idx]=run; run += cnt[idx]; }
  }
}

__global__ __launch_bounds__(256) void k_scatter_perm(const int* __restrict__ ei,
                                                      int* __restrict__ off,
                                                      int* __restrict__ perm){
  int e = blockIdx.x*256 + threadIdx.x;
  if (e < EE){
    int p = atomicAdd(&off[ei[e]], 1);
    perm[p] = e;
  }
}

// ---------------- fused edge pipeline: MLP(32->64->128->192) + segmented scatter ----------
// R8 restructure: block = 256 thr = 4 waves processing ONE shared M=64 edge tile.
// P1/P2/P3 are block-wide GEMMs with N-SPLIT across waves (wave w owns nt tiles
// {w} / {2w,2w+1} / {3w..3w+2}) and each wave iterates all 4 M-tiles. Weight
// fragments are loaded ONCE per 64 edges (was once per 16) -> weight VMEM ÷4
// (8.5 -> 2.1 instr/edge). R7 showed occupancy is not the lever (2x waves, ±0%);
// the target is the CU-shared L1/VMEM service time of tiny-tile weight re-streams.
// LDS map (bytes) — same 53504 total as proven R2 (3 blocks/CU):
//  H1 hi/lo: 0 / 9216            (64 rows x 72 shorts)   ends 18432
//  EA hi/lo: 18432 / 23552       (64 rows x 40 shorts)   ends 28672
//  H2 hi/lo: 18432 / 35840       (alias EA; EA dead at P2) ends 53248
//  F fp32:   0 (64 x 196)        aliases H1+H2, written after last H2 read
//  cut:      53248 (64 f32)
#define O_H1H 0
#define O_H1L 9216
#define O_EAH 18432
#define O_EAL 23552
#define O_H2H 18432
#define O_H2L 35840
#define O_F   0
#define O_CUT 53248
#define SMEM_BYTES 53504

__global__ __launch_bounds__(256, 3) void k_edge_fused(
    const float* __restrict__ ea, const float* __restrict__ ew,
    const int* __restrict__ ei, const int* __restrict__ perm,
    const short* __restrict__ W1h, const short* __restrict__ W1l, const float* __restrict__ b1,
    const short* __restrict__ W2h, const short* __restrict__ W2l, const float* __restrict__ b2,
    const short* __restrict__ W3h, const short* __restrict__ W3l, const float* __restrict__ b3,
    const float* __restrict__ XDi, float* __restrict__ Y)
{
  __shared__ char smem[SMEM_BYTES] __attribute__((aligned(16)));
  const int tid  = threadIdx.x;
  const int w    = tid >> 6;
  const int l    = tid & 63;
  const int quad = l >> 4;
  const int nin  = l & 15;
  const int e0   = blockIdx.x * 64;            // block's 64 sorted edges
  char* sb = smem;

  // ---- P4 edge tabs for this wave's 16 edges (compiler sinks these to P4) ----
  int eT[16], dT[16], sT[16];
  #pragma unroll
  for (int t=0;t<16;t++) eT[t] = perm[e0 + w*16 + t];
  #pragma unroll
  for (int t=0;t<16;t++){ dT[t] = ei[eT[t]]; sT[t] = ei[EE + eT[t]]; }

  // ---- P0: block stages 64 edge_attr rows (hi/lo split) + cutoffs ----
  #pragma unroll
  for (int g=0; g<2; g++){                       // 512 float4 over EA [64][32]
    int gi = tid + g*256;
    int row = gi >> 3, c4 = gi & 7;
    int er = perm[e0 + row];
    float4 v = *(const float4*)&ea[(size_t)er*32 + c4*4];
    int be = row*40 + c4*4;
    short h;
    h = f2bf(v.x); ((short*)(sb+O_EAH))[be+0]=h; ((short*)(sb+O_EAL))[be+0]=f2bf(v.x-bf2f(h));
    h = f2bf(v.y); ((short*)(sb+O_EAH))[be+1]=h; ((short*)(sb+O_EAL))[be+1]=f2bf(v.y-bf2f(h));
    h = f2bf(v.z); ((short*)(sb+O_EAH))[be+2]=h; ((short*)(sb+O_EAL))[be+2]=f2bf(v.z-bf2f(h));
    h = f2bf(v.w); ((short*)(sb+O_EAH))[be+3]=h; ((short*)(sb+O_EAL))[be+3]=f2bf(v.w-bf2f(h));
  }
  if (tid < 64){
    float wv = ew[perm[e0 + tid]];
    float c = 0.5f*(__cosf(wv*0.6283185307179586f)+1.0f);
    ((float*)(sb+O_CUT))[tid] = (wv < 5.0f) ? c : 0.0f;
  }
  __syncthreads();

  // ---- P1: H1 = silu(EA @ W1^T + b1), M=64 N=64 K=32; wave w: nt=w, 4 m-tiles ----
  {
    bf16x8 bh = *(const bf16x8*)&W1h[(w*16+nin)*32 + quad*8];
    bf16x8 bl = *(const bf16x8*)&W1l[(w*16+nin)*32 + quad*8];
    f32x4 acc1[4];
    #pragma unroll
    for (int mt=0; mt<4; mt++){
      bf16x8 ah = *(const bf16x8*)(sb + O_EAH + (mt*16+nin)*80 + quad*16);
      bf16x8 al = *(const bf16x8*)(sb + O_EAL + (mt*16+nin)*80 + quad*16);
      f32x4 z = {0.f,0.f,0.f,0.f};
      acc1[mt] = mfma4(ah, al, bh, bl, z);
    }
    float bb = b1[w*16+nin];
    #pragma unroll
    for (int mt=0; mt<4; mt++){
      #pragma unroll
      for (int r=0; r<4; r++){
        float v = silu_f(acc1[mt][r] + bb);
        int row = mt*16 + quad*4 + r, col = w*16 + nin;
        short hi = f2bf(v); short lo = f2bf(v - bf2f(hi));
        ((short*)(sb+O_H1H))[row*72 + col] = hi;
        ((short*)(sb+O_H1L))[row*72 + col] = lo;
      }
    }
  }
  __syncthreads();

  // ---- P2: H2 = silu(H1 @ W2^T + b2), M=64 N=128 K=64; wave w: nt in {2w,2w+1} ----
  {
    f32x4 acc2[2][4];
    #pragma unroll
    for (int i=0;i<2;i++)
      #pragma unroll
      for (int mt=0;mt<4;mt++){ f32x4 z = {0.f,0.f,0.f,0.f}; acc2[i][mt]=z; }
    #pragma unroll
    for (int kt=0; kt<2; kt++){
      bf16x8 ah[4], al[4];
      #pragma unroll
      for (int mt=0;mt<4;mt++){
        ah[mt] = *(const bf16x8*)(sb + O_H1H + (mt*16+nin)*144 + kt*64 + quad*16);
        al[mt] = *(const bf16x8*)(sb + O_H1L + (mt*16+nin)*144 + kt*64 + quad*16);
      }
      #pragma unroll
      for (int i=0; i<2; i++){
        int nt = w*2 + i;
        bf16x8 bh = *(const bf16x8*)&W2h[(nt*16+nin)*64 + kt*32 + quad*8];
        bf16x8 bl = *(const bf16x8*)&W2l[(nt*16+nin)*64 + kt*32 + quad*8];
        #pragma unroll
        for (int mt=0;mt<4;mt++) acc2[i][mt] = mfma4(ah[mt], al[mt], bh, bl, acc2[i][mt]);
      }
    }
    // H2 aliases EA; all EA reads finished before the post-P1 barrier
    #pragma unroll
    for (int i=0; i<2; i++){
      int nt = w*2 + i;
      float bb = b2[nt*16+nin];
      #pragma unroll
      for (int mt=0; mt<4; mt++){
        #pragma unroll
        for (int r=0; r<4; r++){
          float v = silu_f(acc2[i][mt][r] + bb);
          int row = mt*16 + quad*4 + r, col = nt*16 + nin;
          short hi = f2bf(v); short lo = f2bf(v - bf2f(hi));
          ((short*)(sb+O_H2H))[row*136 + col] = hi;
          ((short*)(sb+O_H2L))[row*136 + col] = lo;
        }
      }
    }
  }
  __syncthreads();

  // ---- P3: F = silu(H2 @ W3^T + b3) * cutoff, M=64 N=192 K=128; nt in {3w..3w+2} ----
  f32x4 acc3[3][4];
  #pragma unroll
  for (int i=0;i<3;i++)
    #pragma unroll
    for (int mt=0;mt<4;mt++){ f32x4 z = {0.f,0.f,0.f,0.f}; acc3[i][mt]=z; }
  #pragma unroll
  for (int kt=0; kt<4; kt++){
    bf16x8 ah[4], al[4];
    #pragma unroll
    for (int mt=0;mt<4;mt++){
      ah[mt] = *(const bf16x8*)(sb + O_H2H + (mt*16+nin)*272 + kt*64 + quad*16);
      al[mt] = *(const bf16x8*)(sb + O_H2L + (mt*16+nin)*272 + kt*64 + quad*16);
    }
    #pragma unroll
    for (int i=0; i<3; i++){
      int nt = w*3 + i;
      bf16x8 bh = *(const bf16x8*)&W3h[(nt*16+nin)*128 + kt*32 + quad*8];
      bf16x8 bl = *(const bf16x8*)&W3l[(nt*16+nin)*128 + kt*32 + quad*8];
      #pragma unroll
      for (int mt=0;mt<4;mt++) acc3[i][mt] = mfma4(ah[mt], al[mt], bh, bl, acc3[i][mt]);
    }
  }
  __syncthreads();               // all H2 reads done; F aliases H1+H2
  #pragma unroll
  for (int i=0; i<3; i++){
    int nt = w*3 + i;
    float bb = b3[nt*16+nin];
    #pragma unroll
    for (int mt=0; mt<4; mt++){
      #pragma unroll
      for (int r=0; r<4; r++){
        int row = mt*16 + quad*4 + r, col = nt*16 + nin;
        float v = silu_f(acc3[i][mt][r] + bb) * ((float*)(sb+O_CUT))[row];
        ((float*)(sb+O_F))[row*196 + col] = v;
      }
    }
  }
  __syncthreads();               // full F visible to P4

  // ---- P4: segmented scatter — wave's 16 sorted edges; run-accumulate in
  //          registers, one atomic flush per run (proven R2 structure) ----
  {
    float acc[9];
    int cur = -1;
    #pragma unroll
    for (int t=0; t<16; t++){
      int el = w*16 + t;
      const float* fb = (const float*)(sb + O_F + el*784 + l*12);
      float f0 = fb[0], f1 = fb[1], f2 = fb[2];
      const float* xb = XDi + (size_t)sT[t]*576 + l;
      if (dT[t] != cur){                       // wave-uniform branch
        if (cur >= 0){
          int dst = cur*64 + l;
          #pragma unroll
          for (int c=0;c<9;c++) atomicAdd(&Y[c*NH+dst], acc[c]);
        }
        cur = dT[t];
        #pragma unroll
        for (int c=0;c<9;c++) acc[c] = 0.f;
      }
      acc[0] += f0*xb[0*64];
      acc[1] += f1*xb[1*64];
      acc[2] += f1*xb[2*64];
      acc[3] += f1*xb[3*64];
      acc[4] += f2*xb[4*64];
      acc[5] += f2*xb[5*64];
      acc[6] += f2*xb[6*64];
      acc[7] += f2*xb[7*64];
      acc[8] += f2*xb[8*64];
    }
    int dst = cur*64 + l;
    #pragma unroll
    for (int c=0;c<9;c++) atomicAdd(&Y[c*NH+dst], acc[c]);
  }
}

// ---------------- node-side fp32 GEMM: 3 plane GEMMs fused in one launch ----
// segments (blocks): [0,196) I-plane M=NN; [196,782) A M=3NN; [782,1954) S M=6NN
__global__ __launch_bounds__(256) void k_gemm3(const float* __restrict__ XDb,
                       const float* __restrict__ WI, const float* __restrict__ WA,
                       const float* __restrict__ WSm, float* __restrict__ XIb){
  constexpr int KSP = 68;   // 64 + 4 pad
  constexpr int F4R = 16;   // 64/4
  __shared__ __align__(16) float sA[128*KSP];
  __shared__ __align__(16) float sW[64*KSP];
  const int b = blockIdx.x;
  const float* In; const float* W; float* Out; int M; int bb;
  if (b < 196)      { In=XDb;                W=WI;  Out=XIb;                M=NN;   bb=b; }
  else if (b < 782) { In=XDb+(size_t)NH;     W=WA;  Out=XIb+(size_t)NH;     M=3*NN; bb=b-196; }
  else              { In=XDb+(size_t)4*NH;   W=WSm; Out=XIb+(size_t)4*NH;   M=6*NN; bb=b-782; }
  const int tid = threadIdx.x;
  const int te = tid >> 4;
  const int to = tid & 15;
  const int e0 = bb * 128;
  float acc[8][4];
  #pragma unroll
  for (int s=0;s<8;s++)
    #pragma unroll
    for (int r=0;r<4;r++) acc[s][r]=0.f;

  #pragma unroll
  for (int g = 0; g < 128*F4R/256; g++){
    int gi = tid + g*256;
    int row = gi / F4R, c4 = gi % F4R;
    float4 v = make_float4(0.f,0.f,0.f,0.f);
    if (e0 + row < M) v = *(const float4*)&In[(size_t)(e0+row)*64 + c4*4];
    int c4p = c4 ^ ((row>>3)&3);
    *(float4*)&sA[row*KSP + c4p*4] = v;
  }
  #pragma unroll
  for (int g = 0; g < 64*F4R/256; g++){
    int gi = tid + g*256;
    int row = gi / F4R, c4 = gi % F4R;
    float4 v = *(const float4*)&W[(size_t)row*64 + c4*4];
    int c4p = c4 ^ ((row>>3)&3);
    *(float4*)&sW[row*KSP + c4p*4] = v;
  }
  __syncthreads();
  #pragma unroll 4
  for (int k4 = 0; k4 < F4R; k4++){
    float4 aa[8], ww[4];
    #pragma unroll
    for (int s=0;s<8;s++){
      int row = te*8+s;
      aa[s] = *(const float4*)&sA[row*KSP + (k4 ^ ((row>>3)&3))*4];
    }
    #pragma unroll
    for (int r=0;r<4;r++){
      int row = to*4+r;
      ww[r] = *(const float4*)&sW[row*KSP + (k4 ^ ((row>>3)&3))*4];
    }
    #pragma unroll
    for (int s=0;s<8;s++)
      #pragma unroll
      for (int r=0;r<4;r++){
        acc[s][r] += aa[s].x*ww[r].x;
        acc[s][r] += aa[s].y*ww[r].y;
        acc[s][r] += aa[s].z*ww[r].z;
        acc[s][r] += aa[s].w*ww[r].w;
      }
  }
  #pragma unroll
  for (int s=0;s<8;s++){
    int eg = e0 + te*8 + s;
    if (eg >= M) continue;
    #pragma unroll
    for (int r=0;r<4;r++){
      int o = to*4 + r;
      Out[(size_t)eg*64 + o] = acc[s][r];
    }
  }
}

__global__ __launch_bounds__(256) void k_combine(const float* __restrict__ XI, const float* __restrict__ Y,
                          float* __restrict__ XM){
  int idx = blockIdx.x*256 + threadIdx.x;
  if (idx >= NH) return;
  float xi[10], yc[10];
  #pragma unroll
  for (int c=0;c<10;c++) xi[c]=XI[c*NH+idx];
  #pragma unroll
  for (int c=0;c<9;c++)  yc[c]=Y[c*NH+idx];
  yc[9] = -(yc[4]+yc[7]);        // S traceless: S22 = -(S00+S11)
  float Xin[9], Ym[9], Am[9], Bm[9];
  build3(Xin, xi); build3(Ym, yc);
  mm3(Am, Ym, Xin);
  mm3(Bm, Xin, Ym);
  float Xn[9]; float n2 = 0.f;
  #pragma unroll
  for (int i=0;i<9;i++){ Xn[i] = Am[i]+Bm[i]; n2 += Xn[i]*Xn[i]; }
  float inv = __fdividef(1.0f, n2 + 1.0f);
  #pragma unroll
  for (int i=0;i<9;i++) Xn[i] *= inv;
  float c[10]; decomp3(Xn, c);
  #pragma unroll
  for (int i=0;i<10;i++) XM[i*NH+idx] = c[i];
}

__global__ __launch_bounds__(256) void k_final(const float* __restrict__ XD, const float* __restrict__ XO,
                        const float* __restrict__ q, float* __restrict__ out){
  int idx = blockIdx.x*256 + threadIdx.x;
  if (idx >= NH) return;
  float xd[10], xo[10];
  #pragma unroll
  for (int c=0;c<10;c++){ xd[c]=XD[c*NH+idx]; xo[c]=XO[c*NH+idx]; }
  float Xn[9], dX[9], D2[9];
  build3(Xn, xd); build3(dX, xo);
  mm3(D2, dX, dX);
  float cf = 1.0f + 0.1f*q[idx>>6];
  float* o = out + (size_t)idx*9;
  #pragma unroll
  for (int i=0;i<9;i++) o[i] = Xn[i] + (dX[i]+D2[i])*cf;
}

extern "C" void kernel_launch(void* const* d_in, const int* in_sizes, int n_in,
                              void* d_out, int out_size, void* d_ws, size_t ws_size,
                              hipStream_t stream) {
  const float* X   = (const float*)d_in[0];
  const int*   ei  = (const int*)  d_in[1];
  const float* ew  = (const float*)d_in[2];
  const float* ea  = (const float*)d_in[3];
  const float* q   = (const float*)d_in[4];
  const float* W1  = (const float*)d_in[5];
  const float* b1  = (const float*)d_in[6];
  const float* W2  = (const float*)d_in[7];
  const float* b2  = (const float*)d_in[8];
  const float* W3  = (const float*)d_in[9];
  const float* b3  = (const float*)d_in[10];
  const float* WIi = (const float*)d_in[11];
  const float* WAi = (const float*)d_in[12];
  const float* WSi = (const float*)d_in[13];
  const float* WIo = (const float*)d_in[14];
  const float* WAo = (const float*)d_in[15];
  const float* WSo = (const float*)d_in[16];
  float* out = (float*)d_out;

  // ---- workspace layout: byte-identical to the proven R2/R3/R7 layout ----
  float* ws = (float*)d_ws;
  float* XD = ws;                        // 10*NH floats
  float* Y  = XD + (size_t)10*NH;        // 10*NH (9 planes used by agg; reused as XO)
  float* XI = Y  + (size_t)10*NH;        // 10*NH (later holds XM)
  short* WS = (short*)(XI + (size_t)10*NH);  // pre-split weights: 69632 shorts
  short* W1h = WS,         *W1l = WS + 2048;
  short* W2h = WS + 4096,  *W2l = WS + 12288;
  short* W3h = WS + 20480, *W3l = WS + 45056;
  int* cnt  = (int*)(WS + 69632);        // 25000 ints
  int* off  = cnt + NNODES;              // 25000 ints
  int* perm = off + NNODES;              // 400000 ints
  float* XDi = (float*)(perm + EE);      // 9*NH floats, node-major gather layout

  hipMemsetAsync(Y, 0, (size_t)9*NH*sizeof(float), stream);
  hipMemsetAsync(cnt, 0, (size_t)NNODES*sizeof(int), stream);
  k_prep_w<<<136, 256, 0, stream>>>(W1, W2, W3, W1h, W1l, W2h, W2l, W3h, W3l);
  k_prep<<<NH/256, 256, 0, stream>>>(X, XD, XDi);

  // counting sort of edges by destination (enables segmented scatter)
  k_hist<<<(EE+255)/256, 256, 0, stream>>>(ei, cnt);
  k_scan<<<1, 256, 0, stream>>>(cnt, off);
  k_scatter_perm<<<(EE+255)/256, 256, 0, stream>>>(ei, off, perm);

  // fused edge pipeline: block-wide M=64 GEMM phases + segmented scatter
  k_edge_fused<<<EE/64, 256, 0, stream>>>(ea, ew, ei, perm, W1h, W1l, b1, W2h, W2l, b2,
                                          W3h, W3l, b3, XDi, Y);

  // Xin = tensor_linear(Xn): 3 plane GEMMs fused in one launch
  k_gemm3<<<1954, 256, 0, stream>>>(XD, WIi, WAi, WSi, XI);

  k_combine<<<NH/256, 256, 0, stream>>>(XI, Y, XI);   // XI now holds XM planes

  float* XO = Y;  // Y consumed; reuse as output-mix buffer
  k_gemm3<<<1954, 256, 0, stream>>>(XI, WIo, WAo, WSo, XO);

  k_final<<<NH/256, 256, 0, stream>>>(XD, XO, q, out);
}

// Round 9
// 649.748 us; speedup vs baseline: 1.8151x; 1.0135x over previous
//
#include <hip/hip_runtime.h>
#include <hip/hip_bf16.h>

#define NN 25000
#define HH 64
#define EE 400000
#define NH (NN*HH)
#define NNODES 25000

typedef __attribute__((ext_vector_type(8))) short bf16x8;
typedef __attribute__((ext_vector_type(4))) float f32x4;

__device__ __forceinline__ float silu_f(float x){
  return __fdividef(x, 1.0f + __expf(-x));
}
// software RNE float->bf16 (kept for cold paths)
__device__ __forceinline__ short f2bf(float x){
  unsigned u = __float_as_uint(x);
  unsigned r = (u + 0x7FFFu + ((u>>16)&1u)) >> 16;
  return (short)r;
}
// hardware float->bf16 (RNE; bit-identical to f2bf, ~4x fewer VALU ops)
__device__ __forceinline__ short f2bfh(float x){
  return __builtin_bit_cast(short, __float2bfloat16(x));
}
__device__ __forceinline__ float bf2f(short h){
  return __uint_as_float(((unsigned)(unsigned short)h)<<16);
}
__device__ __forceinline__ unsigned pk2(short a, short b){
  return ((unsigned)(unsigned short)a) | (((unsigned)(unsigned short)b)<<16);
}
// 4-term split product: (ah+al)(bh+bl) — error ~2^-18 relative
__device__ __forceinline__ f32x4 mfma4(bf16x8 ah, bf16x8 al, bf16x8 bh, bf16x8 bl, f32x4 acc){
  acc = __builtin_amdgcn_mfma_f32_16x16x32_bf16(ah, bh, acc, 0, 0, 0);
  acc = __builtin_amdgcn_mfma_f32_16x16x32_bf16(ah, bl, acc, 0, 0, 0);
  acc = __builtin_amdgcn_mfma_f32_16x16x32_bf16(al, bh, acc, 0, 0, 0);
  acc = __builtin_amdgcn_mfma_f32_16x16x32_bf16(al, bl, acc, 0, 0, 0);
  return acc;
}

__device__ __forceinline__ void mm3(float* __restrict__ C, const float* __restrict__ A,
                                    const float* __restrict__ B){
  #pragma unroll
  for (int i=0;i<3;i++)
    #pragma unroll
    for (int j=0;j<3;j++)
      C[i*3+j] = A[i*3+0]*B[0*3+j] + A[i*3+1]*B[1*3+j] + A[i*3+2]*B[2*3+j];
}
__device__ __forceinline__ void build3(float* __restrict__ M, const float* __restrict__ c){
  M[0] =  c[0]+c[4]; M[1] =  c[1]+c[5]; M[2] =  c[2]+c[6];
  M[3] = -c[1]+c[5]; M[4] =  c[0]+c[7]; M[5] =  c[3]+c[8];
  M[6] = -c[2]+c[6]; M[7] = -c[3]+c[8]; M[8] =  c[0]+c[9];
}
__device__ __forceinline__ void decomp3(const float* __restrict__ M, float* __restrict__ c){
  float I = (M[0]+M[4]+M[8]) * (1.0f/3.0f);
  c[0]=I;
  c[1]=0.5f*(M[1]-M[3]); c[2]=0.5f*(M[2]-M[6]); c[3]=0.5f*(M[5]-M[7]);
  c[4]=M[0]-I; c[5]=0.5f*(M[1]+M[3]); c[6]=0.5f*(M[2]+M[6]);
  c[7]=M[4]-I; c[8]=0.5f*(M[5]+M[7]); c[9]=M[8]-I;
}

// k_prep: normalize + decompose; writes plane-major XD (for GEMMs/final)
// and node-major XDi[node][c=0..8][64] (dense 2304B/node gather layout for P4)
__global__ __launch_bounds__(256) void k_prep(const float* __restrict__ X, float* __restrict__ XD,
                                              float* __restrict__ XDi){
  int idx = blockIdx.x*256 + threadIdx.x;
  if (idx >= NH) return;
  const float* t = X + (size_t)idx*9;
  float m[9];
  float n2 = 0.f;
  #pragma unroll
  for (int i=0;i<9;i++){ m[i] = t[i]; n2 += m[i]*m[i]; }
  float inv = __fdividef(1.0f, n2 + 1.0f);
  #pragma unroll
  for (int i=0;i<9;i++) m[i] *= inv;
  float c[10]; decomp3(m, c);
  #pragma unroll
  for (int i=0;i<10;i++) XD[i*NH + idx] = c[i];
  int node = idx >> 6, lane = idx & 63;
  float* xb = XDi + (size_t)node*576 + lane;   // 576 = 9*64
  #pragma unroll
  for (int i=0;i<9;i++) xb[i*64] = c[i];
}

// pre-split MLP weights into bf16 hi/lo (runs every launch; deterministic)
__global__ __launch_bounds__(256) void k_prep_w(
    const float* __restrict__ W1, const float* __restrict__ W2, const float* __restrict__ W3,
    short* __restrict__ W1h, short* __restrict__ W1l,
    short* __restrict__ W2h, short* __restrict__ W2l,
    short* __restrict__ W3h, short* __restrict__ W3l){
  int i = blockIdx.x*256 + threadIdx.x;
  if (i < 2048){
    float v = W1[i]; short h = f2bf(v); W1h[i]=h; W1l[i]=f2bf(v - bf2f(h));
  } else if (i < 10240){
    int j = i - 2048;
    float v = W2[j]; short h = f2bf(v); W2h[j]=h; W2l[j]=f2bf(v - bf2f(h));
  } else if (i < 34816){
    int j = i - 10240;
    float v = W3[j]; short h = f2bf(v); W3h[j]=h; W3l[j]=f2bf(v - bf2f(h));
  }
}

// ---------------- counting sort of edges by destination node -------------
__global__ __launch_bounds__(256) void k_hist(const int* __restrict__ ei, int* __restrict__ cnt){
  int e = blockIdx.x*256 + threadIdx.x;
  if (e < EE) atomicAdd(&cnt[ei[e]], 1);
}

// exclusive prefix sum over cnt[NNODES] -> off (single workgroup)
__global__ __launch_bounds__(256) void k_scan(const int* __restrict__ cnt, int* __restrict__ off){
  __shared__ int part[256];
  const int tid = threadIdx.x;
  const int base = tid*98;                 // 256*98 = 25088 >= 25000
  int s = 0;
  for (int i=0;i<98;i++){ int idx=base+i; if (idx<NNODES) s += cnt[idx]; }
  part[tid]=s; __syncthreads();
  for (int d=1; d<256; d<<=1){
    int v = (tid>=d)? part[tid-d] : 0;
    __syncthreads();
    part[tid] += v;
    __syncthreads();
  }
  int run = (tid==0)? 0 : part[tid-1];
  for (int i=0;i<98;i++){
    int idx=base+i;
    if (idx<NNODES){ off[idx]=run; run += cnt[idx]; }
  }
}

__global__ __launch_bounds__(256) void k_scatter_perm(const int* __restrict__ ei,
                                                      int* __restrict__ off,
                                                      int* __restrict__ perm){
  int e = blockIdx.x*256 + threadIdx.x;
  if (e < EE){
    int p = atomicAdd(&off[ei[e]], 1);
    perm[p] = e;
  }
}

// ---------------- fused edge pipeline: MLP(32->64->128->192) + segmented scatter ----------
// R8 structure (proven): block = 4 waves, ONE shared M=64 edge tile, block-wide
// GEMM phases with N-split across waves. R9: hardware bf16 cvt (bit-identical
// RNE) + packed uint2 EA-staging stores — targets the 43% VALUBusy.
// LDS map (bytes):
//  H1 hi/lo: 0 / 9216            (64 rows x 72 shorts)   ends 18432
//  EA hi/lo: 18432 / 23552       (64 rows x 40 shorts)   ends 28672
//  H2 hi/lo: 18432 / 35840       (alias EA; EA dead at P2) ends 53248
//  F fp32:   0 (64 x 196)        aliases H1+H2, written after last H2 read
//  cut:      53248 (64 f32)
#define O_H1H 0
#define O_H1L 9216
#define O_EAH 18432
#define O_EAL 23552
#define O_H2H 18432
#define O_H2L 35840
#define O_F   0
#define O_CUT 53248
#define SMEM_BYTES 53504

__global__ __launch_bounds__(256, 3) void k_edge_fused(
    const float* __restrict__ ea, const float* __restrict__ ew,
    const int* __restrict__ ei, const int* __restrict__ perm,
    const short* __restrict__ W1h, const short* __restrict__ W1l, const float* __restrict__ b1,
    const short* __restrict__ W2h, const short* __restrict__ W2l, const float* __restrict__ b2,
    const short* __restrict__ W3h, const short* __restrict__ W3l, const float* __restrict__ b3,
    const float* __restrict__ XDi, float* __restrict__ Y)
{
  __shared__ char smem[SMEM_BYTES] __attribute__((aligned(16)));
  const int tid  = threadIdx.x;
  const int w    = tid >> 6;
  const int l    = tid & 63;
  const int quad = l >> 4;
  const int nin  = l & 15;
  const int e0   = blockIdx.x * 64;            // block's 64 sorted edges
  char* sb = smem;

  // ---- P4 edge tabs for this wave's 16 edges (compiler sinks these to P4) ----
  int eT[16], dT[16], sT[16];
  #pragma unroll
  for (int t=0;t<16;t++) eT[t] = perm[e0 + w*16 + t];
  #pragma unroll
  for (int t=0;t<16;t++){ dT[t] = ei[eT[t]]; sT[t] = ei[EE + eT[t]]; }

  // ---- P0: block stages 64 edge_attr rows (hi/lo split, hw cvt, packed stores) ----
  #pragma unroll
  for (int g=0; g<2; g++){                       // 512 float4 over EA [64][32]
    int gi = tid + g*256;
    int row = gi >> 3, c4 = gi & 7;
    int er = perm[e0 + row];
    float4 v = *(const float4*)&ea[(size_t)er*32 + c4*4];
    int be = row*40 + c4*4;                      // short index
    short h0=f2bfh(v.x), h1=f2bfh(v.y), h2=f2bfh(v.z), h3=f2bfh(v.w);
    uint2 hv, lv;
    hv.x = pk2(h0,h1); hv.y = pk2(h2,h3);
    lv.x = pk2(f2bfh(v.x-bf2f(h0)), f2bfh(v.y-bf2f(h1)));
    lv.y = pk2(f2bfh(v.z-bf2f(h2)), f2bfh(v.w-bf2f(h3)));
    *(uint2*)(sb + O_EAH + 2*be) = hv;
    *(uint2*)(sb + O_EAL + 2*be) = lv;
  }
  if (tid < 64){
    float wv = ew[perm[e0 + tid]];
    float c = 0.5f*(__cosf(wv*0.6283185307179586f)+1.0f);
    ((float*)(sb+O_CUT))[tid] = (wv < 5.0f) ? c : 0.0f;
  }
  __syncthreads();

  // ---- P1: H1 = silu(EA @ W1^T + b1), M=64 N=64 K=32; wave w: nt=w, 4 m-tiles ----
  {
    bf16x8 bh = *(const bf16x8*)&W1h[(w*16+nin)*32 + quad*8];
    bf16x8 bl = *(const bf16x8*)&W1l[(w*16+nin)*32 + quad*8];
    f32x4 acc1[4];
    #pragma unroll
    for (int mt=0; mt<4; mt++){
      bf16x8 ah = *(const bf16x8*)(sb + O_EAH + (mt*16+nin)*80 + quad*16);
      bf16x8 al = *(const bf16x8*)(sb + O_EAL + (mt*16+nin)*80 + quad*16);
      f32x4 z = {0.f,0.f,0.f,0.f};
      acc1[mt] = mfma4(ah, al, bh, bl, z);
    }
    float bb = b1[w*16+nin];
    #pragma unroll
    for (int mt=0; mt<4; mt++){
      #pragma unroll
      for (int r=0; r<4; r++){
        float v = silu_f(acc1[mt][r] + bb);
        int row = mt*16 + quad*4 + r, col = w*16 + nin;
        short hi = f2bfh(v); short lo = f2bfh(v - bf2f(hi));
        ((short*)(sb+O_H1H))[row*72 + col] = hi;
        ((short*)(sb+O_H1L))[row*72 + col] = lo;
      }
    }
  }
  __syncthreads();

  // ---- P2: H2 = silu(H1 @ W2^T + b2), M=64 N=128 K=64; wave w: nt in {2w,2w+1} ----
  {
    f32x4 acc2[2][4];
    #pragma unroll
    for (int i=0;i<2;i++)
      #pragma unroll
      for (int mt=0;mt<4;mt++){ f32x4 z = {0.f,0.f,0.f,0.f}; acc2[i][mt]=z; }
    #pragma unroll
    for (int kt=0; kt<2; kt++){
      bf16x8 ah[4], al[4];
      #pragma unroll
      for (int mt=0;mt<4;mt++){
        ah[mt] = *(const bf16x8*)(sb + O_H1H + (mt*16+nin)*144 + kt*64 + quad*16);
        al[mt] = *(const bf16x8*)(sb + O_H1L + (mt*16+nin)*144 + kt*64 + quad*16);
      }
      #pragma unroll
      for (int i=0; i<2; i++){
        int nt = w*2 + i;
        bf16x8 bh = *(const bf16x8*)&W2h[(nt*16+nin)*64 + kt*32 + quad*8];
        bf16x8 bl = *(const bf16x8*)&W2l[(nt*16+nin)*64 + kt*32 + quad*8];
        #pragma unroll
        for (int mt=0;mt<4;mt++) acc2[i][mt] = mfma4(ah[mt], al[mt], bh, bl, acc2[i][mt]);
      }
    }
    // H2 aliases EA; all EA reads finished before the post-P1 barrier
    #pragma unroll
    for (int i=0; i<2; i++){
      int nt = w*2 + i;
      float bb = b2[nt*16+nin];
      #pragma unroll
      for (int mt=0; mt<4; mt++){
        #pragma unroll
        for (int r=0; r<4; r++){
          float v = silu_f(acc2[i][mt][r] + bb);
          int row = mt*16 + quad*4 + r, col = nt*16 + nin;
          short hi = f2bfh(v); short lo = f2bfh(v - bf2f(hi));
          ((short*)(sb+O_H2H))[row*136 + col] = hi;
          ((short*)(sb+O_H2L))[row*136 + col] = lo;
        }
      }
    }
  }
  __syncthreads();

  // ---- P3: F = silu(H2 @ W3^T + b3) * cutoff, M=64 N=192 K=128; nt in {3w..3w+2} ----
  f32x4 acc3[3][4];
  #pragma unroll
  for (int i=0;i<3;i++)
    #pragma unroll
    for (int mt=0;mt<4;mt++){ f32x4 z = {0.f,0.f,0.f,0.f}; acc3[i][mt]=z; }
  #pragma unroll
  for (int kt=0; kt<4; kt++){
    bf16x8 ah[4], al[4];
    #pragma unroll
    for (int mt=0;mt<4;mt++){
      ah[mt] = *(const bf16x8*)(sb + O_H2H + (mt*16+nin)*272 + kt*64 + quad*16);
      al[mt] = *(const bf16x8*)(sb + O_H2L + (mt*16+nin)*272 + kt*64 + quad*16);
    }
    #pragma unroll
    for (int i=0; i<3; i++){
      int nt = w*3 + i;
      bf16x8 bh = *(const bf16x8*)&W3h[(nt*16+nin)*128 + kt*32 + quad*8];
      bf16x8 bl = *(const bf16x8*)&W3l[(nt*16+nin)*128 + kt*32 + quad*8];
      #pragma unroll
      for (int mt=0;mt<4;mt++) acc3[i][mt] = mfma4(ah[mt], al[mt], bh, bl, acc3[i][mt]);
    }
  }
  __syncthreads();               // all H2 reads done; F aliases H1+H2
  #pragma unroll
  for (int i=0; i<3; i++){
    int nt = w*3 + i;
    float bb = b3[nt*16+nin];
    #pragma unroll
    for (int mt=0; mt<4; mt++){
      #pragma unroll
      for (int r=0; r<4; r++){
        int row = mt*16 + quad*4 + r, col = nt*16 + nin;
        float v = silu_f(acc3[i][mt][r] + bb) * ((float*)(sb+O_CUT))[row];
        ((float*)(sb+O_F))[row*196 + col] = v;
      }
    }
  }
  __syncthreads();               // full F visible to P4

  // ---- P4: segmented scatter — wave's 16 sorted edges; run-accumulate in
  //          registers, one atomic flush per run (proven R2 structure) ----
  {
    float acc[9];
    int cur = -1;
    #pragma unroll
    for (int t=0; t<16; t++){
      int el = w*16 + t;
      const float* fb = (const float*)(sb + O_F + el*784 + l*12);
      float f0 = fb[0], f1 = fb[1], f2 = fb[2];
      const float* xb = XDi + (size_t)sT[t]*576 + l;
      if (dT[t] != cur){                       // wave-uniform branch
        if (cur >= 0){
          int dst = cur*64 + l;
          #pragma unroll
          for (int c=0;c<9;c++) atomicAdd(&Y[c*NH+dst], acc[c]);
        }
        cur = dT[t];
        #pragma unroll
        for (int c=0;c<9;c++) acc[c] = 0.f;
      }
      acc[0] += f0*xb[0*64];
      acc[1] += f1*xb[1*64];
      acc[2] += f1*xb[2*64];
      acc[3] += f1*xb[3*64];
      acc[4] += f2*xb[4*64];
      acc[5] += f2*xb[5*64];
      acc[6] += f2*xb[6*64];
      acc[7] += f2*xb[7*64];
      acc[8] += f2*xb[8*64];
    }
    int dst = cur*64 + l;
    #pragma unroll
    for (int c=0;c<9;c++) atomicAdd(&Y[c*NH+dst], acc[c]);
  }
}

// ---------------- node-side plane GEMMs, MFMA split-bf16, fused in one launch ----
// segments (blocks): [0,196) I-plane M=NN; [196,782) A M=3NN; [782,1954) S M=6NN.
// Per block: M=128 rows x N=64 x K=64. In/W split to bf16 hi/lo on the fly in LDS;
// wave w owns nt=w (16 cols), iterates 8 m-tiles; 4-term mfma (err ~2^-18/product).
// Same row<->buffer mapping as the proven fp32 k_gemm3; same C-layout as proven P1.
__global__ __launch_bounds__(256, 2) void k_gemm3m(const float* __restrict__ XDb,
                       const float* __restrict__ WI, const float* __restrict__ WA,
                       const float* __restrict__ WSm, float* __restrict__ XIb){
  __shared__ short sAh[128*72], sAl[128*72];   // 18432 B each
  __shared__ short sWh[64*72],  sWl[64*72];    //  9216 B each  (total 55296)
  const int b = blockIdx.x;
  const float* In; const float* W; float* Out; int M; int bb;
  if (b < 196)      { In=XDb;                W=WI;  Out=XIb;                M=NN;   bb=b; }
  else if (b < 782) { In=XDb+(size_t)NH;     W=WA;  Out=XIb+(size_t)NH;     M=3*NN; bb=b-196; }
  else              { In=XDb+(size_t)4*NH;   W=WSm; Out=XIb+(size_t)4*NH;   M=6*NN; bb=b-782; }
  const int tid = threadIdx.x;
  const int w    = tid >> 6;
  const int l    = tid & 63;
  const int quad = l >> 4;
  const int nin  = l & 15;
  const int e0 = bb * 128;

  // stage A: 128x64 fp32 -> hi/lo bf16; 2048 float4 over 256 thr = 8 each
  #pragma unroll
  for (int g=0; g<8; g++){
    int gi = tid + g*256;
    int row = gi >> 4, c4 = gi & 15;
    float4 v = make_float4(0.f,0.f,0.f,0.f);
    if (e0 + row < M) v = *(const float4*)&In[(size_t)(e0+row)*64 + c4*4];
    short h0=f2bfh(v.x), h1=f2bfh(v.y), h2=f2bfh(v.z), h3=f2bfh(v.w);
    uint2 hv, lv;
    hv.x = pk2(h0,h1); hv.y = pk2(h2,h3);
    lv.x = pk2(f2bfh(v.x-bf2f(h0)), f2bfh(v.y-bf2f(h1)));
    lv.y = pk2(f2bfh(v.z-bf2f(h2)), f2bfh(v.w-bf2f(h3)));
    int s0 = row*72 + c4*4;                       // short index, 8B-aligned
    *(uint2*)&sAh[s0] = hv;
    *(uint2*)&sAl[s0] = lv;
  }
  // stage W: 64x64 fp32 -> hi/lo; 1024 float4 = 4 each
  #pragma unroll
  for (int g=0; g<4; g++){
    int gi = tid + g*256;
    int row = gi >> 4, c4 = gi & 15;
    float4 v = *(const float4*)&W[(size_t)row*64 + c4*4];
    short h0=f2bfh(v.x), h1=f2bfh(v.y), h2=f2bfh(v.z), h3=f2bfh(v.w);
    uint2 hv, lv;
    hv.x = pk2(h0,h1); hv.y = pk2(h2,h3);
    lv.x = pk2(f2bfh(v.x-bf2f(h0)), f2bfh(v.y-bf2f(h1)));
    lv.y = pk2(f2bfh(v.z-bf2f(h2)), f2bfh(v.w-bf2f(h3)));
    int s0 = row*72 + c4*4;
    *(uint2*)&sWh[s0] = hv;
    *(uint2*)&sWl[s0] = lv;
  }
  __syncthreads();

  f32x4 acc[8];
  #pragma unroll
  for (int mt=0;mt<8;mt++){ f32x4 z = {0.f,0.f,0.f,0.f}; acc[mt]=z; }
  #pragma unroll
  for (int kt=0; kt<2; kt++){
    bf16x8 bh = *(const bf16x8*)&sWh[(w*16+nin)*72 + kt*32 + quad*8];
    bf16x8 bl = *(const bf16x8*)&sWl[(w*16+nin)*72 + kt*32 + quad*8];
    #pragma unroll
    for (int mt=0; mt<8; mt++){
      bf16x8 ah = *(const bf16x8*)&sAh[(mt*16+nin)*72 + kt*32 + quad*8];
      bf16x8 al = *(const bf16x8*)&sAl[(mt*16+nin)*72 + kt*32 + quad*8];
      acc[mt] = mfma4(ah, al, bh, bl, acc[mt]);
    }
  }
  // C-write: row = quad*4+r (+mt*16), col = w*16+nin (proven P1 mapping)
  #pragma unroll
  for (int mt=0; mt<8; mt++){
    #pragma unroll
    for (int r=0; r<4; r++){
      int row = e0 + mt*16 + quad*4 + r;
      if (row < M) Out[(size_t)row*64 + w*16 + nin] = acc[mt][r];
    }
  }
}

__global__ __launch_bounds__(256) void k_combine(const float* __restrict__ XI, const float* __restrict__ Y,
                          float* __restrict__ XM){
  int idx = blockIdx.x*256 + threadIdx.x;
  if (idx >= NH) return;
  float xi[10], yc[10];
  #pragma unroll
  for (int c=0;c<10;c++) xi[c]=XI[c*NH+idx];
  #pragma unroll
  for (int c=0;c<9;c++)  yc[c]=Y[c*NH+idx];
  yc[9] = -(yc[4]+yc[7]);        // S traceless: S22 = -(S00+S11)
  float Xin[9], Ym[9], Am[9], Bm[9];
  build3(Xin, xi); build3(Ym, yc);
  mm3(Am, Ym, Xin);
  mm3(Bm, Xin, Ym);
  float Xn[9]; float n2 = 0.f;
  #pragma unroll
  for (int i=0;i<9;i++){ Xn[i] = Am[i]+Bm[i]; n2 += Xn[i]*Xn[i]; }
  float inv = __fdividef(1.0f, n2 + 1.0f);
  #pragma unroll
  for (int i=0;i<9;i++) Xn[i] *= inv;
  float c[10]; decomp3(Xn, c);
  #pragma unroll
  for (int i=0;i<10;i++) XM[i*NH+idx] = c[i];
}

__global__ __launch_bounds__(256) void k_final(const float* __restrict__ XD, const float* __restrict__ XO,
                        const float* __restrict__ q, float* __restrict__ out){
  int idx = blockIdx.x*256 + threadIdx.x;
  if (idx >= NH) return;
  float xd[10], xo[10];
  #pragma unroll
  for (int c=0;c<10;c++){ xd[c]=XD[c*NH+idx]; xo[c]=XO[c*NH+idx]; }
  float Xn[9], dX[9], D2[9];
  build3(Xn, xd); build3(dX, xo);
  mm3(D2, dX, dX);
  float cf = 1.0f + 0.1f*q[idx>>6];
  float* o = out + (size_t)idx*9;
  #pragma unroll
  for (int i=0;i<9;i++) o[i] = Xn[i] + (dX[i]+D2[i])*cf;
}

extern "C" void kernel_launch(void* const* d_in, const int* in_sizes, int n_in,
                              void* d_out, int out_size, void* d_ws, size_t ws_size,
                              hipStream_t stream) {
  const float* X   = (const float*)d_in[0];
  const int*   ei  = (const int*)  d_in[1];
  const float* ew  = (const float*)d_in[2];
  const float* ea  = (const float*)d_in[3];
  const float* q   = (const float*)d_in[4];
  const float* W1  = (const float*)d_in[5];
  const float* b1  = (const float*)d_in[6];
  const float* W2  = (const float*)d_in[7];
  const float* b2  = (const float*)d_in[8];
  const float* W3  = (const float*)d_in[9];
  const float* b3  = (const float*)d_in[10];
  const float* WIi = (const float*)d_in[11];
  const float* WAi = (const float*)d_in[12];
  const float* WSi = (const float*)d_in[13];
  const float* WIo = (const float*)d_in[14];
  const float* WAo = (const float*)d_in[15];
  const float* WSo = (const float*)d_in[16];
  float* out = (float*)d_out;

  // ---- workspace layout: byte-identical to the proven R2..R8 layout ----
  float* ws = (float*)d_ws;
  float* XD = ws;                        // 10*NH floats
  float* Y  = XD + (size_t)10*NH;        // 10*NH (9 planes used by agg; reused as XO)
  float* XI = Y  + (size_t)10*NH;        // 10*NH (later holds XM)
  short* WS = (short*)(XI + (size_t)10*NH);  // pre-split weights: 69632 shorts
  short* W1h = WS,         *W1l = WS + 2048;
  short* W2h = WS + 4096,  *W2l = WS + 12288;
  short* W3h = WS + 20480, *W3l = WS + 45056;
  int* cnt  = (int*)(WS + 69632);        // 25000 ints
  int* off  = cnt + NNODES;              // 25000 ints
  int* perm = off + NNODES;              // 400000 ints
  float* XDi = (float*)(perm + EE);      // 9*NH floats, node-major gather layout

  hipMemsetAsync(Y, 0, (size_t)9*NH*sizeof(float), stream);
  hipMemsetAsync(cnt, 0, (size_t)NNODES*sizeof(int), stream);
  k_prep_w<<<136, 256, 0, stream>>>(W1, W2, W3, W1h, W1l, W2h, W2l, W3h, W3l);
  k_prep<<<NH/256, 256, 0, stream>>>(X, XD, XDi);

  // counting sort of edges by destination (enables segmented scatter)
  k_hist<<<(EE+255)/256, 256, 0, stream>>>(ei, cnt);
  k_scan<<<1, 256, 0, stream>>>(cnt, off);
  k_scatter_perm<<<(EE+255)/256, 256, 0, stream>>>(ei, off, perm);

  // fused edge pipeline: block-wide M=64 GEMM phases + segmented scatter
  k_edge_fused<<<EE/64, 256, 0, stream>>>(ea, ew, ei, perm, W1h, W1l, b1, W2h, W2l, b2,
                                          W3h, W3l, b3, XDi, Y);

  // Xin = tensor_linear(Xn): 3 plane GEMMs fused in one MFMA launch
  k_gemm3m<<<1954, 256, 0, stream>>>(XD, WIi, WAi, WSi, XI);

  k_combine<<<NH/256, 256, 0, stream>>>(XI, Y, XI);   // XI now holds XM planes

  float* XO = Y;  // Y consumed; reuse as output-mix buffer
  k_gemm3m<<<1954, 256, 0, stream>>>(XI, WIo, WAo, WSo, XO);

  k_final<<<NH/256, 256, 0, stream>>>(XD, XO, q, out);
}